// Round 13
// baseline (80.793 us; speedup 1.0000x reference)
//
#include <hip/hip_runtime.h>
#include <hip/hip_bf16.h>
#include <math.h>

#define NROWS 4096
#define HD 512
#define HEADS 8
#define HDD 64
#define SEQ 1024
#define QSCALE 0.18033688011112042f   // 0.125 * log2(e)

typedef unsigned short u16;
typedef unsigned int u32;
typedef unsigned long long u64;
typedef __attribute__((ext_vector_type(8))) short sh8;   // 8 bf16 (4 VGPRs)
typedef __attribute__((ext_vector_type(4))) float f4;    // MFMA accumulator

__device__ __forceinline__ f4 mfma16(sh8 a, sh8 b, f4 c) {
  return __builtin_amdgcn_mfma_f32_16x16x32_bf16(a, b, c, 0, 0, 0);
}

__device__ __forceinline__ u16 f2bf(float x) {
  union { float f; unsigned u; } v; v.f = x;
  unsigned r = v.u + 0x7fff + ((v.u >> 16) & 1);   // RNE
  return (u16)(r >> 16);
}

// packed fp32x2 -> bf16x2 (lo = first arg), 1 VALU op (T12 recipe)
__device__ __forceinline__ u32 cvt_pk_bf16(float lo, float hi) {
  u32 r;
  asm("v_cvt_pk_bf16_f32 %0, %1, %2" : "=v"(r) : "v"(lo), "v"(hi));
  return r;
}

// XOR swizzle for 128B-row LDS tiles (spread same-column b128 reads)
#define SWZA(r, cb) ((((r) * 128) + (cb)) ^ (((r) & 7) << 4))

// ---------------- K0: prep: circuit -> U -> M[c][12][16][16] ----------------
__global__ __launch_bounds__(256) void k_prep(
    const float* __restrict__ qw, const float* __restrict__ qe,
    const float* __restrict__ qg, const float* __restrict__ qb,
    const float* __restrict__ kw, const float* __restrict__ ke,
    const float* __restrict__ kg, const float* __restrict__ kb,
    const float* __restrict__ vw, const float* __restrict__ ve,
    const float* __restrict__ vg, const float* __restrict__ vb,
    float* __restrict__ Mout) {
  const int c = blockIdx.x;
  const int tid = threadIdx.x;
  __shared__ float aC[32], aS[32];
  __shared__ float GT[60][8];
  __shared__ int   GM[60][2];
  __shared__ float PF[3][16][2];
  __shared__ float SR[16][17], SI[16][17];
  __shared__ float TS[16], TI[16];
  __shared__ float Ur[256], Ui[256];

  const float* w = (c == 0) ? qw : (c == 1) ? kw : vw;
  const float* e = (c == 0) ? qe : (c == 1) ? ke : ve;
  const float* g = (c == 0) ? qg : (c == 1) ? kg : vg;
  const float* b = (c == 0) ? qb : (c == 1) ? kb : vb;

  if (tid < 30) {
    float ang = (tid < 12) ? w[tid] : (tid < 24) ? e[tid - 12]
               : (tid < 27) ? g[tid - 24] : b[tid - 27];
    float s_, c_;
    sincosf(0.5f * ang, &s_, &c_);
    aC[tid] = c_; aS[tid] = s_;
  }
  __syncthreads();

  if (tid < 60) {
    int L = tid / 20, s5 = tid % 20;
    int typ, aidx, M, C;
    if (s5 < 12) {
      int q = s5 / 3; typ = s5 % 3; aidx = L * 4 + q; M = 8 >> q; C = 0;
    } else if (s5 < 16) {
      int q = s5 - 12; typ = 0; aidx = 12 + L * 4 + q;
      C = 8 >> q; M = 8 >> ((q + 1) & 3);
    } else {
      int q = s5 - 16; typ = 0; aidx = 27 + L; M = 8 >> q; C = 0;
    }
    float cc = aC[aidx], ss = aS[aidx];
    float u0r = cc, u0i = 0.f, u1r = 0.f, u1i = 0.f,
          u2r = 0.f, u2i = 0.f, u3r = cc, u3i = 0.f;
    if (typ == 0)      { u1i = -ss; u2i = -ss; }
    else if (typ == 1) { u1r = -ss; u2r = ss; }
    else               { u0i = -ss; u3i = ss; }
    GT[tid][0] = u0r; GT[tid][1] = u0i; GT[tid][2] = u1r; GT[tid][3] = u1i;
    GT[tid][4] = u2r; GT[tid][5] = u2i; GT[tid][6] = u3r; GT[tid][7] = u3i;
    GM[tid][0] = M; GM[tid][1] = C;
  }
  if (tid >= 64 && tid < 112) {
    int idx = tid - 64, L = idx >> 4, a = idx & 15;
    float cg = aC[24 + L], sg = aS[24 + L];
    float c2 = cg * cg - sg * sg, s2 = 2.f * cg * sg;
    float c3 = cg * c2 - sg * s2, s3 = cg * s2 + sg * c2;
    int u = (a ^ (a >> 1)) & 7;
    int n = (u & 1) + ((u >> 1) & 1) + ((u >> 2) & 1);
    PF[L][a][0] = (n == 0 || n == 3) ? c3 : cg;
    PF[L][a][1] = (n == 0) ? -s3 : (n == 1) ? -sg : (n == 2) ? sg : s3;
  }
  for (int i = tid; i < 256; i += 256) {
    SR[i >> 4][i & 15] = (i >> 4) == (i & 15) ? 1.f : 0.f;
    SI[i >> 4][i & 15] = 0.f;
  }
  __syncthreads();

  const int p = tid >> 4, col = tid & 15;
  for (int L = 0; L < 3; ++L) {
    for (int s5 = 0; s5 < 16; ++s5) {
      if (tid < 128) {
        int gi = L * 20 + s5;
        const float* u = GT[gi];
        int M = GM[gi][0], C = GM[gi][1];
        int lo = p & (M - 1);
        int a = ((p - lo) << 1) | lo;
        int bb = a | M;
        bool act = (C == 0) | ((a & C) != 0);
        float ar = SR[a][col], ai = SI[a][col];
        float br = SR[bb][col], bi = SI[bb][col];
        float nar = u[0]*ar - u[1]*ai + u[2]*br - u[3]*bi;
        float nai = u[0]*ai + u[1]*ar + u[2]*bi + u[3]*br;
        float nbr = u[4]*ar - u[5]*ai + u[6]*br - u[7]*bi;
        float nbi = u[4]*ai + u[5]*ar + u[6]*bi + u[7]*br;
        SR[a][col]  = act ? nar : ar;  SI[a][col]  = act ? nai : ai;
        SR[bb][col] = act ? nbr : br;  SI[bb][col] = act ? nbi : bi;
      }
      __syncthreads();
    }
    if (tid < 16) {
      float sR = 0.f, sI = 0.f;
      for (int a = 0; a < 16; ++a) { sR += SR[a][tid]; sI += SI[a][tid]; }
      TS[tid] = sR * 0.125f; TI[tid] = sI * 0.125f;
    }
    __syncthreads();
    if (tid < 128) {
      for (int k = 0; k < 2; ++k) {
        int a = 2 * p + k;
        float vr = SR[a][col] - TS[col];
        float vi = SI[a][col] - TI[col];
        float pc = PF[L][a][0], ps = PF[L][a][1];
        SR[a][col] = vr * pc - vi * ps;
        SI[a][col] = vr * ps + vi * pc;
      }
    }
    __syncthreads();
    for (int s5 = 16; s5 < 20; ++s5) {
      if (tid < 128) {
        int gi = L * 20 + s5;
        const float* u = GT[gi];
        int M = GM[gi][0];
        int lo = p & (M - 1);
        int a = ((p - lo) << 1) | lo;
        int bb = a | M;
        float ar = SR[a][col], ai = SI[a][col];
        float br = SR[bb][col], bi = SI[bb][col];
        SR[a][col]  = u[0]*ar - u[1]*ai + u[2]*br - u[3]*bi;
        SI[a][col]  = u[0]*ai + u[1]*ar + u[2]*bi + u[3]*br;
        SR[bb][col] = u[4]*ar - u[5]*ai + u[6]*br - u[7]*bi;
        SI[bb][col] = u[4]*ai + u[5]*ar + u[6]*bi + u[7]*br;
      }
      __syncthreads();
    }
  }

  for (int i = tid; i < 256; i += 256) {
    Ur[i] = SR[i >> 4][i & 15];
    Ui[i] = SI[i >> 4][i & 15];
  }
  __syncthreads();

  if (tid < 192) {
    const int j = tid >> 4, a = tid & 15;
    const int typ = j >> 2;
    const int Mm = 8 >> (j & 3);
    float ax[4] = {0.f,0.f,0.f,0.f}, ay[4] = {0.f,0.f,0.f,0.f},
          az[4] = {0.f,0.f,0.f,0.f}, aw[4] = {0.f,0.f,0.f,0.f};
#pragma clang loop unroll_count(4)
    for (int k = 0; k < 16; ++k) {
      float uar = Ur[k * 16 + a], uai = Ui[k * 16 + a];
      int k2; float cR, cI;
      if (typ == 0)      { k2 = k;      float z = (k & Mm) ? -1.f : 1.f; cR = z*uar; cI = z*uai; }
      else if (typ == 1) { k2 = k ^ Mm; cR = uar; cI = uai; }
      else               { k2 = k ^ Mm; float sg = (k & Mm) ? 1.f : -1.f; cR = sg*uai; cI = -sg*uar; }
      const float* ur2 = Ur + k2 * 16;
      const float* ui2 = Ui + k2 * 16;
#pragma unroll
      for (int i = 0; i < 4; ++i) {
        ax[i] += cR * ur2[i*4+0] + cI * ui2[i*4+0];
        ay[i] += cR * ur2[i*4+1] + cI * ui2[i*4+1];
        az[i] += cR * ur2[i*4+2] + cI * ui2[i*4+2];
        aw[i] += cR * ur2[i*4+3] + cI * ui2[i*4+3];
      }
    }
    float* dst = Mout + ((c * 12 + j) * 16 + a) * 16;
#pragma unroll
    for (int i = 0; i < 4; ++i)
      ((float4*)dst)[i] = make_float4(ax[i], ay[i], az[i], aw[i]);
  }
}

// ---- K1: front: LN -> psi -> t -> QKV, 1024 blocks x 4 rows ----
__global__ __launch_bounds__(256) void k_front(const float* __restrict__ x,
    const float* __restrict__ Wp, const float* __restrict__ bp,
    const float* __restrict__ ln_g, const float* __restrict__ ln_b,
    const float* __restrict__ Mg,
    const float* __restrict__ Wq, const float* __restrict__ bq,
    const float* __restrict__ Wk, const float* __restrict__ bk,
    const float* __restrict__ Wv, const float* __restrict__ bv,
    u16* __restrict__ Qo, u16* __restrict__ Ko, u16* __restrict__ Vto) {
  const int rb = blockIdx.x;
  const int tid = threadIdx.x;
  const int w = tid >> 6, lane = tid & 63;
  __shared__ float pl[4][4];
  __shared__ float psil[4][16];
  __shared__ float tt[3][4][12];

  {
    const float* xr = x + (rb * 4 + w) * HD + lane * 8;
    float4 xa = *(const float4*)xr, xb = *(const float4*)(xr + 4);
    float acc[4];
#pragma unroll
    for (int j = 0; j < 4; ++j) {
      const float* wr = Wp + j * HD + lane * 8;
      float4 wa = *(const float4*)wr, wb = *(const float4*)(wr + 4);
      acc[j] = xa.x*wa.x + xa.y*wa.y + xa.z*wa.z + xa.w*wa.w
             + xb.x*wb.x + xb.y*wb.y + xb.z*wb.z + xb.w*wb.w;
    }
#pragma unroll
    for (int j = 0; j < 4; ++j)
#pragma unroll
      for (int off = 32; off >= 1; off >>= 1)
        acc[j] += __shfl_xor(acc[j], off);
    if (lane == 0) {
      float v0 = tanhf(acc[0] + bp[0]);
      float v1 = tanhf(acc[1] + bp[1]);
      float v2 = tanhf(acc[2] + bp[2]);
      float v3 = tanhf(acc[3] + bp[3]);
      float mu = 0.25f * (v0 + v1 + v2 + v3);
      float d0 = v0 - mu, d1 = v1 - mu, d2 = v2 - mu, d3 = v3 - mu;
      float inv = rsqrtf(0.25f * (d0*d0 + d1*d1 + d2*d2 + d3*d3) + 1e-5f);
      pl[w][0] = d0 * inv * ln_g[0] + ln_b[0];
      pl[w][1] = d1 * inv * ln_g[1] + ln_b[1];
      pl[w][2] = d2 * inv * ln_g[2] + ln_b[2];
      pl[w][3] = d3 * inv * ln_g[3] + ln_b[3];
    }
  }
  __syncthreads();

  if (tid < 4) {
    float cs[4], sn[4];
    sincosf(0.5f * pl[tid][0], &sn[0], &cs[0]);
    sincosf(0.5f * pl[tid][1], &sn[1], &cs[1]);
    sincosf(0.5f * pl[tid][2], &sn[2], &cs[2]);
    sincosf(0.5f * pl[tid][3], &sn[3], &cs[3]);
    float q01[4] = {cs[0]*cs[1], cs[0]*sn[1], sn[0]*cs[1], sn[0]*sn[1]};
    float q23[4] = {cs[2]*cs[3], cs[2]*sn[3], sn[2]*cs[3], sn[2]*sn[3]};
#pragma unroll
    for (int a = 0; a < 16; ++a) psil[tid][a] = q01[a >> 2] * q23[a & 3];
  }
  __syncthreads();

  if (tid < 144) {
    const int c = tid / 48, rem = tid - c * 48, j = rem >> 2, r = rem & 3;
    float psi[16];
#pragma unroll
    for (int a = 0; a < 16; ++a) psi[a] = psil[r][a];
    const float4* Mj = (const float4*)(Mg + (c * 12 + j) * 256);
    float y = 0.f;
#pragma unroll
    for (int a = 0; a < 16; ++a) {
      float rsum = 0.f;
#pragma unroll
      for (int i = 0; i < 4; ++i) {
        float4 m4 = Mj[a * 4 + i];
        rsum += m4.x*psi[i*4] + m4.y*psi[i*4+1] + m4.z*psi[i*4+2] + m4.w*psi[i*4+3];
      }
      y += psi[a] * rsum;
    }
    tt[c][r][j] = y;
  }
  __syncthreads();

  const int o0 = tid * 2;
  const int b = rb >> 8, ss0 = (rb & 255) * 4;
  const int h = o0 >> 6, d = o0 & 63;
#pragma unroll
  for (int c = 0; c < 3; ++c) {
    const float* W  = (c == 0) ? Wq : (c == 1) ? Wk : Wv;
    const float* bb = (c == 0) ? bq : (c == 1) ? bk : bv;
    float4 w0a = *(const float4*)(W + o0 * 12);
    float4 w0b = *(const float4*)(W + o0 * 12 + 4);
    float4 w0c = *(const float4*)(W + o0 * 12 + 8);
    float4 w1a = *(const float4*)(W + o0 * 12 + 12);
    float4 w1b = *(const float4*)(W + o0 * 12 + 16);
    float4 w1c = *(const float4*)(W + o0 * 12 + 20);
    float b0 = bb[o0], b1 = bb[o0 + 1];
    float r0[4], r1[4];
#pragma unroll
    for (int r = 0; r < 4; ++r) {
      const float* t = tt[c][r];
      r0[r] = b0 + t[0]*w0a.x + t[1]*w0a.y + t[2]*w0a.z + t[3]*w0a.w
                 + t[4]*w0b.x + t[5]*w0b.y + t[6]*w0b.z + t[7]*w0b.w
                 + t[8]*w0c.x + t[9]*w0c.y + t[10]*w0c.z + t[11]*w0c.w;
      r1[r] = b1 + t[0]*w1a.x + t[1]*w1a.y + t[2]*w1a.z + t[3]*w1a.w
                 + t[4]*w1b.x + t[5]*w1b.y + t[6]*w1b.z + t[7]*w1b.w
                 + t[8]*w1c.x + t[9]*w1c.y + t[10]*w1c.z + t[11]*w1c.w;
    }
    if (c == 0) {
      u16* qrow = Qo + ((b * HEADS + h) * SEQ + ss0) * HDD + d;
#pragma unroll
      for (int r = 0; r < 4; ++r)
        *(u32*)(qrow + r * HDD) =
            (u32)f2bf(r0[r] * QSCALE) | ((u32)f2bf(r1[r] * QSCALE) << 16);
    } else if (c == 1) {
      u16* krow = Ko + ((b * HEADS + h) * SEQ + ss0) * HDD + d;
#pragma unroll
      for (int r = 0; r < 4; ++r)
        *(u32*)(krow + r * HDD) = (u32)f2bf(r0[r]) | ((u32)f2bf(r1[r]) << 16);
    } else {
      u64 v0 = (u64)((u32)f2bf(r0[0]) | ((u32)f2bf(r0[1]) << 16)) |
               ((u64)((u32)f2bf(r0[2]) | ((u32)f2bf(r0[3]) << 16)) << 32);
      u64 v1 = (u64)((u32)f2bf(r1[0]) | ((u32)f2bf(r1[1]) << 16)) |
               ((u64)((u32)f2bf(r1[2]) | ((u32)f2bf(r1[3]) << 16)) << 32);
      *(u64*)(Vto + (b * 512 + o0) * SEQ + ss0) = v0;
      *(u64*)(Vto + (b * 512 + o0 + 1) * SEQ + ss0) = v1;
    }
  }
}

// ---------------- K2: split-K MFMA flash attention, swapped QK^T -------------
// grid (16 qt, 32 bh, 2 ks); 4 waves; chunk 64 double-buffered; 40 KB LDS.
__global__ __launch_bounds__(256) void k_attn_mfma(const u16* __restrict__ Q,
    const u16* __restrict__ K, const u16* __restrict__ Vt,
    float* __restrict__ Op, float* __restrict__ Lp) {
  const int bh = blockIdx.y, qt = blockIdx.x, ks = blockIdx.z;
  const int tid = threadIdx.x, w = tid >> 6, l = tid & 63;
  const int lr = l & 15, lh = l >> 4;

  __shared__ u16 Kl[2][64 * 64];
  __shared__ u16 Vl[2][64 * 64];
  __shared__ u16 Pl[4][16 * 64];

  const u16* Qb = Q + (bh * SEQ + qt * 64) * HDD;
  const u16* Kb = K + bh * SEQ * HDD;
  const u16* Vb = Vt + bh * HDD * SEQ;
  const int CH0 = ks * 8;
  u16* Plw = Pl[w];

  sh8 qf[2];
#pragma unroll
  for (int kk = 0; kk < 2; ++kk)
    qf[kk] = *(const sh8*)(Qb + (w * 16 + lr) * HDD + kk * 32 + lh * 8);

  f4 oacc[4];
  float lsum = 0.f;
#pragma unroll
  for (int n = 0; n < 4; ++n) oacc[n] = (f4){0.f, 0.f, 0.f, 0.f};

  sh8 kreg[2], vreg[2];

#define STAGE_LOAD(ch) { \
    _Pragma("unroll") \
    for (int i = 0; i < 2; ++i) { \
      int idx = i * 256 + tid; \
      kreg[i] = *(const sh8*)(Kb + ((ch) * 64 + (idx >> 3)) * HDD + (idx & 7) * 8); \
      vreg[i] = *(const sh8*)(Vb + (idx >> 3) * SEQ + (ch) * 64 + (idx & 7) * 8); \
    } }
#define STAGE_WRITE(buf) { \
    _Pragma("unroll") \
    for (int i = 0; i < 2; ++i) { \
      int idx = i * 256 + tid; \
      *(sh8*)((char*)Kl[buf] + SWZA(idx >> 3, (idx & 7) * 16)) = kreg[i]; \
      *(sh8*)((char*)Vl[buf] + SWZA(idx >> 3, (idx & 7) * 16)) = vreg[i]; \
    } }

  STAGE_LOAD(CH0)
  STAGE_WRITE(0)
  __syncthreads();

  for (int it = 0; it < 8; ++it) {
    const int cur = it & 1;
    if (it < 7) STAGE_LOAD(CH0 + it + 1)

    f4 sacc[4];
#pragma unroll
    for (int n = 0; n < 4; ++n) sacc[n] = (f4){0.f, 0.f, 0.f, 0.f};
    __builtin_amdgcn_s_setprio(1);
#pragma unroll
    for (int kk = 0; kk < 2; ++kk) {
#pragma unroll
      for (int n = 0; n < 4; ++n) {
        sh8 kf = *(const sh8*)((const char*)Kl[cur] + SWZA(n * 16 + lr, kk * 64 + lh * 16));
        sacc[n] = mfma16(kf, qf[kk], sacc[n]);
      }
    }
    __builtin_amdgcn_s_setprio(0);

#pragma unroll
    for (int n = 0; n < 4; ++n) {
      float p0 = exp2f(sacc[n][0]);
      float p1 = exp2f(sacc[n][1]);
      float p2 = exp2f(sacc[n][2]);
      float p3 = exp2f(sacc[n][3]);
      lsum += (p0 + p1) + (p2 + p3);
      u32 w0 = cvt_pk_bf16(p0, p1);
      u32 w1 = cvt_pk_bf16(p2, p3);
      *(uint2*)((char*)Plw + SWZA(lr, n * 32 + lh * 8)) = make_uint2(w0, w1);
    }

    __builtin_amdgcn_s_setprio(1);
#pragma unroll
    for (int kk = 0; kk < 2; ++kk) {
      sh8 pf = *(const sh8*)((const char*)Plw + SWZA(lr, kk * 64 + lh * 16));
#pragma unroll
      for (int n = 0; n < 4; ++n) {
        sh8 vf = *(const sh8*)((const char*)Vl[cur] + SWZA(n * 16 + lr, kk * 64 + lh * 16));
        oacc[n] = mfma16(pf, vf, oacc[n]);
      }
    }
    __builtin_amdgcn_s_setprio(0);

    if (it < 7) STAGE_WRITE(cur ^ 1)
    __syncthreads();
  }
#undef STAGE_LOAD
#undef STAGE_WRITE

  lsum += __shfl_xor(lsum, 16);
  lsum += __shfl_xor(lsum, 32);

  const int bb = bh >> 3, h = bh & 7;
#pragma unroll
  for (int r = 0; r < 4; ++r) {
    int row = qt * 64 + w * 16 + lh * 4 + r;
    float* orow = Op + ((ks * NROWS + bb * SEQ + row) * HD) + h * 64;
#pragma unroll
    for (int n = 0; n < 4; ++n)
      orow[n * 16 + lr] = oacc[n][r];
  }
  if (l < 16)
    Lp[(ks * 32 + bh) * SEQ + qt * 64 + w * 16 + lr] = lsum;
}

// ---- K3: combine: ab = bf16( (O0+O1) / (l0+l1) ), streaming ----
__global__ __launch_bounds__(256) void k_combine(const float* __restrict__ Op,
    const float* __restrict__ Lp, u16* __restrict__ ab) {
  const int idx = (blockIdx.x * 256 + threadIdx.x) * 8;   // elem in [0, 4096*512)
  const int row = idx >> 9, col = idx & 511;
  const int bb = row >> 10, srow = row & 1023, h = col >> 6;
  float l0 = Lp[(bb * 8 + h) * SEQ + srow];
  float l1 = Lp[(32 + bb * 8 + h) * SEQ + srow];
  float linv = 1.f / (l0 + l1);
  const float* o0 = Op + idx;
  const float* o1 = o0 + NROWS * HD;
  float4 a0 = *(const float4*)o0, a1 = *(const float4*)(o0 + 4);
  float4 b0 = *(const float4*)o1, b1 = *(const float4*)(o1 + 4);
  uint4 v;
  v.x = cvt_pk_bf16((a0.x + b0.x) * linv, (a0.y + b0.y) * linv);
  v.y = cvt_pk_bf16((a0.z + b0.z) * linv, (a0.w + b0.w) * linv);
  v.z = cvt_pk_bf16((a1.x + b1.x) * linv, (a1.y + b1.y) * linv);
  v.w = cvt_pk_bf16((a1.z + b1.z) * linv, (a1.w + b1.w) * linv);
  *(uint4*)(ab + idx) = v;
}

// ---- K4: out = a @ Wo^T + bo (MFMA, Wo converted in staging; round-10 ver) --
__global__ __launch_bounds__(256) void k_oproj_mfma(const u16* __restrict__ A,
    const float* __restrict__ W, const float* __restrict__ bo,
    float* __restrict__ out) {
  const int nb = blockIdx.x, ob = blockIdx.y;
  const int tid = threadIdx.x, w = tid >> 6, l = tid & 63;
  const int lr = l & 15, lh = l >> 4;
  __shared__ u16 Al[64 * 64];
  __shared__ u16 Wl[64 * 64];
  f4 acc[4];
#pragma unroll
  for (int n = 0; n < 4; ++n) acc[n] = (f4){0.f, 0.f, 0.f, 0.f};
  for (int ch = 0; ch < 8; ++ch) {
    __syncthreads();
#pragma unroll
    for (int i = 0; i < 2; ++i) {
      int idx = i * 256 + tid;
      int r = idx >> 3, c8 = idx & 7;
      *(sh8*)((char*)Al + SWZA(r, c8 * 16)) =
          *(const sh8*)(A + (nb * 64 + r) * HD + ch * 64 + c8 * 8);
      const float* wp = W + (ob * 64 + r) * HD + ch * 64 + c8 * 8;
      float4 f0 = *(const float4*)wp;
      float4 f1 = *(const float4*)(wp + 4);
      uint4 wv;
      wv.x = cvt_pk_bf16(f0.x, f0.y);
      wv.y = cvt_pk_bf16(f0.z, f0.w);
      wv.z = cvt_pk_bf16(f1.x, f1.y);
      wv.w = cvt_pk_bf16(f1.z, f1.w);
      *(uint4*)((char*)Wl + SWZA(r, c8 * 16)) = wv;
    }
    __syncthreads();
#pragma unroll
    for (int kk = 0; kk < 2; ++kk) {
      sh8 af = *(const sh8*)((const char*)Al + SWZA(w * 16 + lr, kk * 64 + lh * 16));
#pragma unroll
      for (int n = 0; n < 4; ++n) {
        sh8 wf = *(const sh8*)((const char*)Wl + SWZA(n * 16 + lr, kk * 64 + lh * 16));
        acc[n] = mfma16(af, wf, acc[n]);
      }
    }
  }
#pragma unroll
  for (int r = 0; r < 4; ++r) {
    int row = nb * 64 + w * 16 + lh * 4 + r;
#pragma unroll
    for (int n = 0; n < 4; ++n) {
      int col = ob * 64 + n * 16 + lr;
      out[row * HD + col] = acc[n][r] + bo[col];
    }
  }
}

// ---------------- launch ----------------
extern "C" void kernel_launch(void* const* d_in, const int* in_sizes, int n_in,
                              void* d_out, int out_size, void* d_ws, size_t ws_size,
                              hipStream_t stream) {
  const float* x    = (const float*)d_in[0];
  const float* Wp   = (const float*)d_in[1];
  const float* bp   = (const float*)d_in[2];
  const float* ln_g = (const float*)d_in[3];
  const float* ln_b = (const float*)d_in[4];
  const float* qw   = (const float*)d_in[5];
  const float* qe   = (const float*)d_in[6];
  const float* qg   = (const float*)d_in[7];
  const float* qb_  = (const float*)d_in[8];
  const float* kw   = (const float*)d_in[9];
  const float* ke   = (const float*)d_in[10];
  const float* kg   = (const float*)d_in[11];
  const float* kb_  = (const float*)d_in[12];
  const float* vw   = (const float*)d_in[13];
  const float* ve   = (const float*)d_in[14];
  const float* vg   = (const float*)d_in[15];
  const float* vb_  = (const float*)d_in[16];
  const float* Wq   = (const float*)d_in[17];
  const float* bq   = (const float*)d_in[18];
  const float* Wk   = (const float*)d_in[19];
  const float* bk   = (const float*)d_in[20];
  const float* Wv   = (const float*)d_in[21];
  const float* bv   = (const float*)d_in[22];
  const float* Wo   = (const float*)d_in[23];
  const float* bo   = (const float*)d_in[24];

  float* ws   = (float*)d_ws;
  float* Mbuf = ws;                        // 9216 f
  u16* qb  = (u16*)(Mbuf + 9216);          // 32*1024*64 u16
  u16* kb  = qb + 32 * SEQ * HDD;
  u16* vtb = kb + 32 * SEQ * HDD;
  float* Opart = (float*)(vtb + 32 * SEQ * HDD);   // 2*4096*512 f32
  float* Lpart = Opart + 2 * NROWS * HD;           // 2*32*1024 f32
  u16* ab = (u16*)(Lpart + 2 * 32 * SEQ);          // 4096*512 u16

  k_prep<<<3, 256, 0, stream>>>(qw, qe, qg, qb_, kw, ke, kg, kb_,
                                vw, ve, vg, vb_, Mbuf);
  k_front<<<NROWS / 4, 256, 0, stream>>>(x, Wp, bp, ln_g, ln_b, Mbuf,
                                         Wq, bq, Wk, bk, Wv, bv, qb, kb, vtb);
  dim3 ga(SEQ / 64, 32, 2);
  k_attn_mfma<<<ga, 256, 0, stream>>>(qb, kb, vtb, Opart, Lpart);
  k_combine<<<NROWS * HD / 2048, 256, 0, stream>>>(Opart, Lpart, ab);
  dim3 go(NROWS / 64, HD / 64);
  k_oproj_mfma<<<go, 256, 0, stream>>>(ab, Wo, bo, (float*)d_out);
}

// Round 14
// 74.091 us; speedup vs baseline: 1.0905x; 1.0905x over previous
//
#include <hip/hip_runtime.h>
#include <hip/hip_bf16.h>
#include <math.h>

#define NROWS 4096
#define HD 512
#define HEADS 8
#define HDD 64
#define SEQ 1024
#define QSCALE 0.18033688011112042f   // 0.125 * log2(e)

typedef unsigned short u16;
typedef unsigned int u32;
typedef unsigned long long u64;
typedef __attribute__((ext_vector_type(8))) short sh8;   // 8 bf16 (4 VGPRs)
typedef __attribute__((ext_vector_type(4))) float f4;    // MFMA accumulator

__device__ __forceinline__ f4 mfma16(sh8 a, sh8 b, f4 c) {
  return __builtin_amdgcn_mfma_f32_16x16x32_bf16(a, b, c, 0, 0, 0);
}

__device__ __forceinline__ u16 f2bf(float x) {
  union { float f; unsigned u; } v; v.f = x;
  unsigned r = v.u + 0x7fff + ((v.u >> 16) & 1);   // RNE
  return (u16)(r >> 16);
}

// packed fp32x2 -> bf16x2 (lo = first arg), 1 VALU op (T12 recipe)
__device__ __forceinline__ u32 cvt_pk_bf16(float lo, float hi) {
  u32 r;
  asm("v_cvt_pk_bf16_f32 %0, %1, %2" : "=v"(r) : "v"(lo), "v"(hi));
  return r;
}

// XOR swizzle for 128B-row LDS tiles (spread same-column b128 reads)
#define SWZA(r, cb) ((((r) * 128) + (cb)) ^ (((r) & 7) << 4))

// ---------------- K0: prep: circuit -> U -> M[c][12][16][16] ----------------
__global__ __launch_bounds__(256) void k_prep(
    const float* __restrict__ qw, const float* __restrict__ qe,
    const float* __restrict__ qg, const float* __restrict__ qb,
    const float* __restrict__ kw, const float* __restrict__ ke,
    const float* __restrict__ kg, const float* __restrict__ kb,
    const float* __restrict__ vw, const float* __restrict__ ve,
    const float* __restrict__ vg, const float* __restrict__ vb,
    float* __restrict__ Mout) {
  const int c = blockIdx.x;
  const int tid = threadIdx.x;
  __shared__ float aC[32], aS[32];
  __shared__ float GT[60][8];
  __shared__ int   GM[60][2];
  __shared__ float PF[3][16][2];
  __shared__ float SR[16][17], SI[16][17];
  __shared__ float TS[16], TI[16];
  __shared__ float Ur[256], Ui[256];

  const float* w = (c == 0) ? qw : (c == 1) ? kw : vw;
  const float* e = (c == 0) ? qe : (c == 1) ? ke : ve;
  const float* g = (c == 0) ? qg : (c == 1) ? kg : vg;
  const float* b = (c == 0) ? qb : (c == 1) ? kb : vb;

  if (tid < 30) {
    float ang = (tid < 12) ? w[tid] : (tid < 24) ? e[tid - 12]
               : (tid < 27) ? g[tid - 24] : b[tid - 27];
    float s_, c_;
    sincosf(0.5f * ang, &s_, &c_);
    aC[tid] = c_; aS[tid] = s_;
  }
  __syncthreads();

  if (tid < 60) {
    int L = tid / 20, s5 = tid % 20;
    int typ, aidx, M, C;
    if (s5 < 12) {
      int q = s5 / 3; typ = s5 % 3; aidx = L * 4 + q; M = 8 >> q; C = 0;
    } else if (s5 < 16) {
      int q = s5 - 12; typ = 0; aidx = 12 + L * 4 + q;
      C = 8 >> q; M = 8 >> ((q + 1) & 3);
    } else {
      int q = s5 - 16; typ = 0; aidx = 27 + L; M = 8 >> q; C = 0;
    }
    float cc = aC[aidx], ss = aS[aidx];
    float u0r = cc, u0i = 0.f, u1r = 0.f, u1i = 0.f,
          u2r = 0.f, u2i = 0.f, u3r = cc, u3i = 0.f;
    if (typ == 0)      { u1i = -ss; u2i = -ss; }
    else if (typ == 1) { u1r = -ss; u2r = ss; }
    else               { u0i = -ss; u3i = ss; }
    GT[tid][0] = u0r; GT[tid][1] = u0i; GT[tid][2] = u1r; GT[tid][3] = u1i;
    GT[tid][4] = u2r; GT[tid][5] = u2i; GT[tid][6] = u3r; GT[tid][7] = u3i;
    GM[tid][0] = M; GM[tid][1] = C;
  }
  if (tid >= 64 && tid < 112) {
    int idx = tid - 64, L = idx >> 4, a = idx & 15;
    float cg = aC[24 + L], sg = aS[24 + L];
    float c2 = cg * cg - sg * sg, s2 = 2.f * cg * sg;
    float c3 = cg * c2 - sg * s2, s3 = cg * s2 + sg * c2;
    int u = (a ^ (a >> 1)) & 7;
    int n = (u & 1) + ((u >> 1) & 1) + ((u >> 2) & 1);
    PF[L][a][0] = (n == 0 || n == 3) ? c3 : cg;
    PF[L][a][1] = (n == 0) ? -s3 : (n == 1) ? -sg : (n == 2) ? sg : s3;
  }
  for (int i = tid; i < 256; i += 256) {
    SR[i >> 4][i & 15] = (i >> 4) == (i & 15) ? 1.f : 0.f;
    SI[i >> 4][i & 15] = 0.f;
  }
  __syncthreads();

  const int p = tid >> 4, col = tid & 15;
  for (int L = 0; L < 3; ++L) {
    for (int s5 = 0; s5 < 16; ++s5) {
      if (tid < 128) {
        int gi = L * 20 + s5;
        const float* u = GT[gi];
        int M = GM[gi][0], C = GM[gi][1];
        int lo = p & (M - 1);
        int a = ((p - lo) << 1) | lo;
        int bb = a | M;
        bool act = (C == 0) | ((a & C) != 0);
        float ar = SR[a][col], ai = SI[a][col];
        float br = SR[bb][col], bi = SI[bb][col];
        float nar = u[0]*ar - u[1]*ai + u[2]*br - u[3]*bi;
        float nai = u[0]*ai + u[1]*ar + u[2]*bi + u[3]*br;
        float nbr = u[4]*ar - u[5]*ai + u[6]*br - u[7]*bi;
        float nbi = u[4]*ai + u[5]*ar + u[6]*bi + u[7]*br;
        SR[a][col]  = act ? nar : ar;  SI[a][col]  = act ? nai : ai;
        SR[bb][col] = act ? nbr : br;  SI[bb][col] = act ? nbi : bi;
      }
      __syncthreads();
    }
    if (tid < 16) {
      float sR = 0.f, sI = 0.f;
      for (int a = 0; a < 16; ++a) { sR += SR[a][tid]; sI += SI[a][tid]; }
      TS[tid] = sR * 0.125f; TI[tid] = sI * 0.125f;
    }
    __syncthreads();
    if (tid < 128) {
      for (int k = 0; k < 2; ++k) {
        int a = 2 * p + k;
        float vr = SR[a][col] - TS[col];
        float vi = SI[a][col] - TI[col];
        float pc = PF[L][a][0], ps = PF[L][a][1];
        SR[a][col] = vr * pc - vi * ps;
        SI[a][col] = vr * ps + vi * pc;
      }
    }
    __syncthreads();
    for (int s5 = 16; s5 < 20; ++s5) {
      if (tid < 128) {
        int gi = L * 20 + s5;
        const float* u = GT[gi];
        int M = GM[gi][0];
        int lo = p & (M - 1);
        int a = ((p - lo) << 1) | lo;
        int bb = a | M;
        float ar = SR[a][col], ai = SI[a][col];
        float br = SR[bb][col], bi = SI[bb][col];
        SR[a][col]  = u[0]*ar - u[1]*ai + u[2]*br - u[3]*bi;
        SI[a][col]  = u[0]*ai + u[1]*ar + u[2]*bi + u[3]*br;
        SR[bb][col] = u[4]*ar - u[5]*ai + u[6]*br - u[7]*bi;
        SI[bb][col] = u[4]*ai + u[5]*ar + u[6]*bi + u[7]*br;
      }
      __syncthreads();
    }
  }

  for (int i = tid; i < 256; i += 256) {
    Ur[i] = SR[i >> 4][i & 15];
    Ui[i] = SI[i >> 4][i & 15];
  }
  __syncthreads();

  if (tid < 192) {
    const int j = tid >> 4, a = tid & 15;
    const int typ = j >> 2;
    const int Mm = 8 >> (j & 3);
    float ax[4] = {0.f,0.f,0.f,0.f}, ay[4] = {0.f,0.f,0.f,0.f},
          az[4] = {0.f,0.f,0.f,0.f}, aw[4] = {0.f,0.f,0.f,0.f};
#pragma clang loop unroll_count(4)
    for (int k = 0; k < 16; ++k) {
      float uar = Ur[k * 16 + a], uai = Ui[k * 16 + a];
      int k2; float cR, cI;
      if (typ == 0)      { k2 = k;      float z = (k & Mm) ? -1.f : 1.f; cR = z*uar; cI = z*uai; }
      else if (typ == 1) { k2 = k ^ Mm; cR = uar; cI = uai; }
      else               { k2 = k ^ Mm; float sg = (k & Mm) ? 1.f : -1.f; cR = sg*uai; cI = -sg*uar; }
      const float* ur2 = Ur + k2 * 16;
      const float* ui2 = Ui + k2 * 16;
#pragma unroll
      for (int i = 0; i < 4; ++i) {
        ax[i] += cR * ur2[i*4+0] + cI * ui2[i*4+0];
        ay[i] += cR * ur2[i*4+1] + cI * ui2[i*4+1];
        az[i] += cR * ur2[i*4+2] + cI * ui2[i*4+2];
        aw[i] += cR * ur2[i*4+3] + cI * ui2[i*4+3];
      }
    }
    float* dst = Mout + ((c * 12 + j) * 16 + a) * 16;
#pragma unroll
    for (int i = 0; i < 4; ++i)
      ((float4*)dst)[i] = make_float4(ax[i], ay[i], az[i], aw[i]);
  }
}

// ---- K1: front: LN -> psi -> t -> QKV, 1024 blocks x 4 rows ----
__global__ __launch_bounds__(256) void k_front(const float* __restrict__ x,
    const float* __restrict__ Wp, const float* __restrict__ bp,
    const float* __restrict__ ln_g, const float* __restrict__ ln_b,
    const float* __restrict__ Mg,
    const float* __restrict__ Wq, const float* __restrict__ bq,
    const float* __restrict__ Wk, const float* __restrict__ bk,
    const float* __restrict__ Wv, const float* __restrict__ bv,
    u16* __restrict__ Qo, u16* __restrict__ Ko, u16* __restrict__ Vto) {
  const int rb = blockIdx.x;
  const int tid = threadIdx.x;
  const int w = tid >> 6, lane = tid & 63;
  __shared__ float pl[4][4];
  __shared__ float psil[4][16];
  __shared__ float tt[3][4][12];

  {
    const float* xr = x + (rb * 4 + w) * HD + lane * 8;
    float4 xa = *(const float4*)xr, xb = *(const float4*)(xr + 4);
    float acc[4];
#pragma unroll
    for (int j = 0; j < 4; ++j) {
      const float* wr = Wp + j * HD + lane * 8;
      float4 wa = *(const float4*)wr, wb = *(const float4*)(wr + 4);
      acc[j] = xa.x*wa.x + xa.y*wa.y + xa.z*wa.z + xa.w*wa.w
             + xb.x*wb.x + xb.y*wb.y + xb.z*wb.z + xb.w*wb.w;
    }
#pragma unroll
    for (int j = 0; j < 4; ++j)
#pragma unroll
      for (int off = 32; off >= 1; off >>= 1)
        acc[j] += __shfl_xor(acc[j], off);
    if (lane == 0) {
      float v0 = tanhf(acc[0] + bp[0]);
      float v1 = tanhf(acc[1] + bp[1]);
      float v2 = tanhf(acc[2] + bp[2]);
      float v3 = tanhf(acc[3] + bp[3]);
      float mu = 0.25f * (v0 + v1 + v2 + v3);
      float d0 = v0 - mu, d1 = v1 - mu, d2 = v2 - mu, d3 = v3 - mu;
      float inv = rsqrtf(0.25f * (d0*d0 + d1*d1 + d2*d2 + d3*d3) + 1e-5f);
      pl[w][0] = d0 * inv * ln_g[0] + ln_b[0];
      pl[w][1] = d1 * inv * ln_g[1] + ln_b[1];
      pl[w][2] = d2 * inv * ln_g[2] + ln_b[2];
      pl[w][3] = d3 * inv * ln_g[3] + ln_b[3];
    }
  }
  __syncthreads();

  if (tid < 4) {
    float cs[4], sn[4];
    sincosf(0.5f * pl[tid][0], &sn[0], &cs[0]);
    sincosf(0.5f * pl[tid][1], &sn[1], &cs[1]);
    sincosf(0.5f * pl[tid][2], &sn[2], &cs[2]);
    sincosf(0.5f * pl[tid][3], &sn[3], &cs[3]);
    float q01[4] = {cs[0]*cs[1], cs[0]*sn[1], sn[0]*cs[1], sn[0]*sn[1]};
    float q23[4] = {cs[2]*cs[3], cs[2]*sn[3], sn[2]*cs[3], sn[2]*sn[3]};
#pragma unroll
    for (int a = 0; a < 16; ++a) psil[tid][a] = q01[a >> 2] * q23[a & 3];
  }
  __syncthreads();

  if (tid < 144) {
    const int c = tid / 48, rem = tid - c * 48, j = rem >> 2, r = rem & 3;
    float psi[16];
#pragma unroll
    for (int a = 0; a < 16; ++a) psi[a] = psil[r][a];
    const float4* Mj = (const float4*)(Mg + (c * 12 + j) * 256);
    float y = 0.f;
#pragma unroll
    for (int a = 0; a < 16; ++a) {
      float rsum = 0.f;
#pragma unroll
      for (int i = 0; i < 4; ++i) {
        float4 m4 = Mj[a * 4 + i];
        rsum += m4.x*psi[i*4] + m4.y*psi[i*4+1] + m4.z*psi[i*4+2] + m4.w*psi[i*4+3];
      }
      y += psi[a] * rsum;
    }
    tt[c][r][j] = y;
  }
  __syncthreads();

  const int o0 = tid * 2;
  const int b = rb >> 8, ss0 = (rb & 255) * 4;
  const int h = o0 >> 6, d = o0 & 63;
#pragma unroll
  for (int c = 0; c < 3; ++c) {
    const float* W  = (c == 0) ? Wq : (c == 1) ? Wk : Wv;
    const float* bb = (c == 0) ? bq : (c == 1) ? bk : bv;
    float4 w0a = *(const float4*)(W + o0 * 12);
    float4 w0b = *(const float4*)(W + o0 * 12 + 4);
    float4 w0c = *(const float4*)(W + o0 * 12 + 8);
    float4 w1a = *(const float4*)(W + o0 * 12 + 12);
    float4 w1b = *(const float4*)(W + o0 * 12 + 16);
    float4 w1c = *(const float4*)(W + o0 * 12 + 20);
    float b0 = bb[o0], b1 = bb[o0 + 1];
    float r0[4], r1[4];
#pragma unroll
    for (int r = 0; r < 4; ++r) {
      const float* t = tt[c][r];
      r0[r] = b0 + t[0]*w0a.x + t[1]*w0a.y + t[2]*w0a.z + t[3]*w0a.w
                 + t[4]*w0b.x + t[5]*w0b.y + t[6]*w0b.z + t[7]*w0b.w
                 + t[8]*w0c.x + t[9]*w0c.y + t[10]*w0c.z + t[11]*w0c.w;
      r1[r] = b1 + t[0]*w1a.x + t[1]*w1a.y + t[2]*w1a.z + t[3]*w1a.w
                 + t[4]*w1b.x + t[5]*w1b.y + t[6]*w1b.z + t[7]*w1b.w
                 + t[8]*w1c.x + t[9]*w1c.y + t[10]*w1c.z + t[11]*w1c.w;
    }
    if (c == 0) {
      u16* qrow = Qo + ((b * HEADS + h) * SEQ + ss0) * HDD + d;
#pragma unroll
      for (int r = 0; r < 4; ++r)
        *(u32*)(qrow + r * HDD) =
            (u32)f2bf(r0[r] * QSCALE) | ((u32)f2bf(r1[r] * QSCALE) << 16);
    } else if (c == 1) {
      u16* krow = Ko + ((b * HEADS + h) * SEQ + ss0) * HDD + d;
#pragma unroll
      for (int r = 0; r < 4; ++r)
        *(u32*)(krow + r * HDD) = (u32)f2bf(r0[r]) | ((u32)f2bf(r1[r]) << 16);
    } else {
      u64 v0 = (u64)((u32)f2bf(r0[0]) | ((u32)f2bf(r0[1]) << 16)) |
               ((u64)((u32)f2bf(r0[2]) | ((u32)f2bf(r0[3]) << 16)) << 32);
      u64 v1 = (u64)((u32)f2bf(r1[0]) | ((u32)f2bf(r1[1]) << 16)) |
               ((u64)((u32)f2bf(r1[2]) | ((u32)f2bf(r1[3]) << 16)) << 32);
      *(u64*)(Vto + (b * 512 + o0) * SEQ + ss0) = v0;
      *(u64*)(Vto + (b * 512 + o0 + 1) * SEQ + ss0) = v1;
    }
  }
}

// ---------------- K2: MFMA flash attention, swapped QK^T, full-K ------------
// grid 512 (XCD-swizzled -> (qt, bh)); 4 waves; chunk 64 dbuf; 40 KB LDS.
// In-kernel normalization, bf16 output [B*S][512].
__global__ __launch_bounds__(256) void k_attn_mfma(const u16* __restrict__ Q,
    const u16* __restrict__ K, const u16* __restrict__ Vt,
    u16* __restrict__ Ob) {
  // T1 bijective XCD swizzle: 16 qt-blocks of a bh stay on one XCD's L2
  const int lin = (blockIdx.x & 7) * 64 + (blockIdx.x >> 3);
  const int bh = lin >> 4, qt = lin & 15;
  const int tid = threadIdx.x, w = tid >> 6, l = tid & 63;
  const int lr = l & 15, lh = l >> 4;

  __shared__ u16 Kl[2][64 * 64];
  __shared__ u16 Vl[2][64 * 64];
  __shared__ u16 Pl[4][16 * 64];

  const u16* Qb = Q + (bh * SEQ + qt * 64) * HDD;
  const u16* Kb = K + bh * SEQ * HDD;
  const u16* Vb = Vt + bh * HDD * SEQ;
  u16* Plw = Pl[w];

  sh8 qf[2];
#pragma unroll
  for (int kk = 0; kk < 2; ++kk)
    qf[kk] = *(const sh8*)(Qb + (w * 16 + lr) * HDD + kk * 32 + lh * 8);

  f4 oacc[4];
  float lsum = 0.f;                  // partial row-sum for q = lr
#pragma unroll
  for (int n = 0; n < 4; ++n) oacc[n] = (f4){0.f, 0.f, 0.f, 0.f};

  sh8 kreg[2], vreg[2];

#define STAGE_LOAD(ch) { \
    _Pragma("unroll") \
    for (int i = 0; i < 2; ++i) { \
      int idx = i * 256 + tid; \
      kreg[i] = *(const sh8*)(Kb + ((ch) * 64 + (idx >> 3)) * HDD + (idx & 7) * 8); \
      vreg[i] = *(const sh8*)(Vb + (idx >> 3) * SEQ + (ch) * 64 + (idx & 7) * 8); \
    } }
#define STAGE_WRITE(buf) { \
    _Pragma("unroll") \
    for (int i = 0; i < 2; ++i) { \
      int idx = i * 256 + tid; \
      *(sh8*)((char*)Kl[buf] + SWZA(idx >> 3, (idx & 7) * 16)) = kreg[i]; \
      *(sh8*)((char*)Vl[buf] + SWZA(idx >> 3, (idx & 7) * 16)) = vreg[i]; \
    } }

  STAGE_LOAD(0)
  STAGE_WRITE(0)
  __syncthreads();

  for (int it = 0; it < 16; ++it) {
    const int cur = it & 1;
    if (it < 15) STAGE_LOAD(it + 1)      // issue early; lands under compute

    // S^T = K Q^T : sacc[n][r] = S[q=lr][key = n*16 + lh*4 + r]
    f4 sacc[4];
#pragma unroll
    for (int n = 0; n < 4; ++n) sacc[n] = (f4){0.f, 0.f, 0.f, 0.f};
    __builtin_amdgcn_s_setprio(1);
#pragma unroll
    for (int kk = 0; kk < 2; ++kk) {
#pragma unroll
      for (int n = 0; n < 4; ++n) {
        sh8 kf = *(const sh8*)((const char*)Kl[cur] + SWZA(n * 16 + lr, kk * 64 + lh * 16));
        sacc[n] = mfma16(kf, qf[kk], sacc[n]);
      }
    }
    __builtin_amdgcn_s_setprio(0);

    // P = 2^S -> packed b64 LDS writes; lane-local partial sums
#pragma unroll
    for (int n = 0; n < 4; ++n) {
      float p0 = exp2f(sacc[n][0]);
      float p1 = exp2f(sacc[n][1]);
      float p2 = exp2f(sacc[n][2]);
      float p3 = exp2f(sacc[n][3]);
      lsum += (p0 + p1) + (p2 + p3);
      u32 w0 = cvt_pk_bf16(p0, p1);
      u32 w1 = cvt_pk_bf16(p2, p3);
      *(uint2*)((char*)Plw + SWZA(lr, n * 32 + lh * 8)) = make_uint2(w0, w1);
    }

    // O += P V
    __builtin_amdgcn_s_setprio(1);
#pragma unroll
    for (int kk = 0; kk < 2; ++kk) {
      sh8 pf = *(const sh8*)((const char*)Plw + SWZA(lr, kk * 64 + lh * 16));
#pragma unroll
      for (int n = 0; n < 4; ++n) {
        sh8 vf = *(const sh8*)((const char*)Vl[cur] + SWZA(n * 16 + lr, kk * 64 + lh * 16));
        oacc[n] = mfma16(pf, vf, oacc[n]);
      }
    }
    __builtin_amdgcn_s_setprio(0);

    if (it < 15) STAGE_WRITE(cur ^ 1)
    __syncthreads();
  }
#undef STAGE_LOAD
#undef STAGE_WRITE

  // total lsum for q = lr (reduce the 4 lh replicas)
  lsum += __shfl_xor(lsum, 16);
  lsum += __shfl_xor(lsum, 32);

  const int bb = bh >> 3, h = bh & 7;
#pragma unroll
  for (int r = 0; r < 4; ++r) {
    int row = qt * 64 + w * 16 + lh * 4 + r;
    float inv = 1.f / __shfl(lsum, lh * 4 + r);    // sum for q = lh*4+r
    u16* orow = Ob + (bb * SEQ + row) * HD + h * 64;
#pragma unroll
    for (int n = 0; n < 4; ++n)
      orow[n * 16 + lr] = f2bf(oacc[n][r] * inv);
  }
}

// ---- K3: out = a @ Wo^T + bo (MFMA, Wo converted in staging) ----
__global__ __launch_bounds__(256) void k_oproj_mfma(const u16* __restrict__ A,
    const float* __restrict__ W, const float* __restrict__ bo,
    float* __restrict__ out) {
  const int nb = blockIdx.x, ob = blockIdx.y;
  const int tid = threadIdx.x, w = tid >> 6, l = tid & 63;
  const int lr = l & 15, lh = l >> 4;
  __shared__ u16 Al[64 * 64];
  __shared__ u16 Wl[64 * 64];
  f4 acc[4];
#pragma unroll
  for (int n = 0; n < 4; ++n) acc[n] = (f4){0.f, 0.f, 0.f, 0.f};
  for (int ch = 0; ch < 8; ++ch) {
    __syncthreads();
#pragma unroll
    for (int i = 0; i < 2; ++i) {
      int idx = i * 256 + tid;
      int r = idx >> 3, c8 = idx & 7;
      *(sh8*)((char*)Al + SWZA(r, c8 * 16)) =
          *(const sh8*)(A + (nb * 64 + r) * HD + ch * 64 + c8 * 8);
      const float* wp = W + (ob * 64 + r) * HD + ch * 64 + c8 * 8;
      float4 f0 = *(const float4*)wp;
      float4 f1 = *(const float4*)(wp + 4);
      uint4 wv;
      wv.x = cvt_pk_bf16(f0.x, f0.y);
      wv.y = cvt_pk_bf16(f0.z, f0.w);
      wv.z = cvt_pk_bf16(f1.x, f1.y);
      wv.w = cvt_pk_bf16(f1.z, f1.w);
      *(uint4*)((char*)Wl + SWZA(r, c8 * 16)) = wv;
    }
    __syncthreads();
#pragma unroll
    for (int kk = 0; kk < 2; ++kk) {
      sh8 af = *(const sh8*)((const char*)Al + SWZA(w * 16 + lr, kk * 64 + lh * 16));
#pragma unroll
      for (int n = 0; n < 4; ++n) {
        sh8 wf = *(const sh8*)((const char*)Wl + SWZA(n * 16 + lr, kk * 64 + lh * 16));
        acc[n] = mfma16(af, wf, acc[n]);
      }
    }
  }
#pragma unroll
  for (int r = 0; r < 4; ++r) {
    int row = nb * 64 + w * 16 + lh * 4 + r;
#pragma unroll
    for (int n = 0; n < 4; ++n) {
      int col = ob * 64 + n * 16 + lr;
      out[row * HD + col] = acc[n][r] + bo[col];
    }
  }
}

// ---------------- launch ----------------
extern "C" void kernel_launch(void* const* d_in, const int* in_sizes, int n_in,
                              void* d_out, int out_size, void* d_ws, size_t ws_size,
                              hipStream_t stream) {
  const float* x    = (const float*)d_in[0];
  const float* Wp   = (const float*)d_in[1];
  const float* bp   = (const float*)d_in[2];
  const float* ln_g = (const float*)d_in[3];
  const float* ln_b = (const float*)d_in[4];
  const float* qw   = (const float*)d_in[5];
  const float* qe   = (const float*)d_in[6];
  const float* qg   = (const float*)d_in[7];
  const float* qb_  = (const float*)d_in[8];
  const float* kw   = (const float*)d_in[9];
  const float* ke   = (const float*)d_in[10];
  const float* kg   = (const float*)d_in[11];
  const float* kb_  = (const float*)d_in[12];
  const float* vw   = (const float*)d_in[13];
  const float* ve   = (const float*)d_in[14];
  const float* vg   = (const float*)d_in[15];
  const float* vb_  = (const float*)d_in[16];
  const float* Wq   = (const float*)d_in[17];
  const float* bq   = (const float*)d_in[18];
  const float* Wk   = (const float*)d_in[19];
  const float* bk   = (const float*)d_in[20];
  const float* Wv   = (const float*)d_in[21];
  const float* bv   = (const float*)d_in[22];
  const float* Wo   = (const float*)d_in[23];
  const float* bo   = (const float*)d_in[24];

  float* ws   = (float*)d_ws;
  float* Mbuf = ws;                        // 9216 f
  u16* qb  = (u16*)(Mbuf + 9216);          // 32*1024*64 u16
  u16* kb  = qb + 32 * SEQ * HDD;
  u16* vtb = kb + 32 * SEQ * HDD;
  u16* ab  = vtb + 32 * SEQ * HDD;         // 4096*512 u16

  k_prep<<<3, 256, 0, stream>>>(qw, qe, qg, qb_, kw, ke, kg, kb_,
                                vw, ve, vg, vb_, Mbuf);
  k_front<<<NROWS / 4, 256, 0, stream>>>(x, Wp, bp, ln_g, ln_b, Mbuf,
                                         Wq, bq, Wk, bk, Wv, bv, qb, kb, vtb);
  k_attn_mfma<<<512, 256, 0, stream>>>(qb, kb, vtb, ab);
  dim3 go(NROWS / 64, HD / 64);
  k_oproj_mfma<<<go, 256, 0, stream>>>(ab, Wo, bo, (float*)d_out);
}

// Round 15
// 73.590 us; speedup vs baseline: 1.0979x; 1.0068x over previous
//
#include <hip/hip_runtime.h>
#include <hip/hip_bf16.h>
#include <math.h>

#define NROWS 4096
#define HD 512
#define HEADS 8
#define HDD 64
#define SEQ 1024
#define QSCALE 0.18033688011112042f   // 0.125 * log2(e)

typedef unsigned short u16;
typedef unsigned int u32;
typedef unsigned long long u64;
typedef __attribute__((ext_vector_type(8))) short sh8;   // 8 bf16 (4 VGPRs)
typedef __attribute__((ext_vector_type(4))) float f4;    // MFMA accumulator

__device__ __forceinline__ f4 mfma16(sh8 a, sh8 b, f4 c) {
  return __builtin_amdgcn_mfma_f32_16x16x32_bf16(a, b, c, 0, 0, 0);
}

__device__ __forceinline__ u16 f2bf(float x) {
  union { float f; unsigned u; } v; v.f = x;
  unsigned r = v.u + 0x7fff + ((v.u >> 16) & 1);   // RNE
  return (u16)(r >> 16);
}

// packed fp32x2 -> bf16x2 (lo = first arg), 1 VALU op (T12 recipe)
__device__ __forceinline__ u32 cvt_pk_bf16(float lo, float hi) {
  u32 r;
  asm("v_cvt_pk_bf16_f32 %0, %1, %2" : "=v"(r) : "v"(lo), "v"(hi));
  return r;
}

// XOR swizzle for 128B-row LDS tiles (spread same-column b128 reads)
#define SWZA(r, cb) ((((r) * 128) + (cb)) ^ (((r) & 7) << 4))

// ---------------- K0: prep ----------------
// blocks 0..2 : circuit -> U -> M[c][12][16][16]
// blocks 3..10: convert Wo (fp32 512x512) -> bf16 once (kills 64x redundant
//               per-oproj-block conversion)
__global__ __launch_bounds__(256) void k_prep(
    const float* __restrict__ qw, const float* __restrict__ qe,
    const float* __restrict__ qg, const float* __restrict__ qb,
    const float* __restrict__ kw, const float* __restrict__ ke,
    const float* __restrict__ kg, const float* __restrict__ kb,
    const float* __restrict__ vw, const float* __restrict__ ve,
    const float* __restrict__ vg, const float* __restrict__ vb,
    const float* __restrict__ Wo, float* __restrict__ Mout,
    u16* __restrict__ Wob) {
  const int c = blockIdx.x;
  const int tid = threadIdx.x;

  if (c >= 3) {                        // ---- Wo conversion ----
    const int base = (c - 3) * 32768 + tid * 128;   // elems (8 blocks x 32768)
#pragma unroll
    for (int i = 0; i < 16; ++i) {
      const float* src = Wo + base + i * 8;
      float4 f0 = *(const float4*)src;
      float4 f1 = *(const float4*)(src + 4);
      uint4 v;
      v.x = cvt_pk_bf16(f0.x, f0.y);
      v.y = cvt_pk_bf16(f0.z, f0.w);
      v.z = cvt_pk_bf16(f1.x, f1.y);
      v.w = cvt_pk_bf16(f1.z, f1.w);
      *(uint4*)(Wob + base + i * 8) = v;
    }
    return;
  }

  __shared__ float aC[32], aS[32];
  __shared__ float GT[60][8];
  __shared__ int   GM[60][2];
  __shared__ float PF[3][16][2];
  __shared__ float SR[16][17], SI[16][17];
  __shared__ float TS[16], TI[16];
  __shared__ float Ur[256], Ui[256];

  const float* w = (c == 0) ? qw : (c == 1) ? kw : vw;
  const float* e = (c == 0) ? qe : (c == 1) ? ke : ve;
  const float* g = (c == 0) ? qg : (c == 1) ? kg : vg;
  const float* b = (c == 0) ? qb : (c == 1) ? kb : vb;

  if (tid < 30) {
    float ang = (tid < 12) ? w[tid] : (tid < 24) ? e[tid - 12]
               : (tid < 27) ? g[tid - 24] : b[tid - 27];
    float s_, c_;
    sincosf(0.5f * ang, &s_, &c_);
    aC[tid] = c_; aS[tid] = s_;
  }
  __syncthreads();

  if (tid < 60) {
    int L = tid / 20, s5 = tid % 20;
    int typ, aidx, M, C;
    if (s5 < 12) {
      int q = s5 / 3; typ = s5 % 3; aidx = L * 4 + q; M = 8 >> q; C = 0;
    } else if (s5 < 16) {
      int q = s5 - 12; typ = 0; aidx = 12 + L * 4 + q;
      C = 8 >> q; M = 8 >> ((q + 1) & 3);
    } else {
      int q = s5 - 16; typ = 0; aidx = 27 + L; M = 8 >> q; C = 0;
    }
    float cc = aC[aidx], ss = aS[aidx];
    float u0r = cc, u0i = 0.f, u1r = 0.f, u1i = 0.f,
          u2r = 0.f, u2i = 0.f, u3r = cc, u3i = 0.f;
    if (typ == 0)      { u1i = -ss; u2i = -ss; }
    else if (typ == 1) { u1r = -ss; u2r = ss; }
    else               { u0i = -ss; u3i = ss; }
    GT[tid][0] = u0r; GT[tid][1] = u0i; GT[tid][2] = u1r; GT[tid][3] = u1i;
    GT[tid][4] = u2r; GT[tid][5] = u2i; GT[tid][6] = u3r; GT[tid][7] = u3i;
    GM[tid][0] = M; GM[tid][1] = C;
  }
  if (tid >= 64 && tid < 112) {
    int idx = tid - 64, L = idx >> 4, a = idx & 15;
    float cg = aC[24 + L], sg = aS[24 + L];
    float c2 = cg * cg - sg * sg, s2 = 2.f * cg * sg;
    float c3 = cg * c2 - sg * s2, s3 = cg * s2 + sg * c2;
    int u = (a ^ (a >> 1)) & 7;
    int n = (u & 1) + ((u >> 1) & 1) + ((u >> 2) & 1);
    PF[L][a][0] = (n == 0 || n == 3) ? c3 : cg;
    PF[L][a][1] = (n == 0) ? -s3 : (n == 1) ? -sg : (n == 2) ? sg : s3;
  }
  for (int i = tid; i < 256; i += 256) {
    SR[i >> 4][i & 15] = (i >> 4) == (i & 15) ? 1.f : 0.f;
    SI[i >> 4][i & 15] = 0.f;
  }
  __syncthreads();

  const int p = tid >> 4, col = tid & 15;
  for (int L = 0; L < 3; ++L) {
    for (int s5 = 0; s5 < 16; ++s5) {
      if (tid < 128) {
        int gi = L * 20 + s5;
        const float* u = GT[gi];
        int M = GM[gi][0], C = GM[gi][1];
        int lo = p & (M - 1);
        int a = ((p - lo) << 1) | lo;
        int bb = a | M;
        bool act = (C == 0) | ((a & C) != 0);
        float ar = SR[a][col], ai = SI[a][col];
        float br = SR[bb][col], bi = SI[bb][col];
        float nar = u[0]*ar - u[1]*ai + u[2]*br - u[3]*bi;
        float nai = u[0]*ai + u[1]*ar + u[2]*bi + u[3]*br;
        float nbr = u[4]*ar - u[5]*ai + u[6]*br - u[7]*bi;
        float nbi = u[4]*ai + u[5]*ar + u[6]*bi + u[7]*br;
        SR[a][col]  = act ? nar : ar;  SI[a][col]  = act ? nai : ai;
        SR[bb][col] = act ? nbr : br;  SI[bb][col] = act ? nbi : bi;
      }
      __syncthreads();
    }
    if (tid < 16) {
      float sR = 0.f, sI = 0.f;
      for (int a = 0; a < 16; ++a) { sR += SR[a][tid]; sI += SI[a][tid]; }
      TS[tid] = sR * 0.125f; TI[tid] = sI * 0.125f;
    }
    __syncthreads();
    if (tid < 128) {
      for (int k = 0; k < 2; ++k) {
        int a = 2 * p + k;
        float vr = SR[a][col] - TS[col];
        float vi = SI[a][col] - TI[col];
        float pc = PF[L][a][0], ps = PF[L][a][1];
        SR[a][col] = vr * pc - vi * ps;
        SI[a][col] = vr * ps + vi * pc;
      }
    }
    __syncthreads();
    for (int s5 = 16; s5 < 20; ++s5) {
      if (tid < 128) {
        int gi = L * 20 + s5;
        const float* u = GT[gi];
        int M = GM[gi][0];
        int lo = p & (M - 1);
        int a = ((p - lo) << 1) | lo;
        int bb = a | M;
        float ar = SR[a][col], ai = SI[a][col];
        float br = SR[bb][col], bi = SI[bb][col];
        SR[a][col]  = u[0]*ar - u[1]*ai + u[2]*br - u[3]*bi;
        SI[a][col]  = u[0]*ai + u[1]*ar + u[2]*bi + u[3]*br;
        SR[bb][col] = u[4]*ar - u[5]*ai + u[6]*br - u[7]*bi;
        SI[bb][col] = u[4]*ai + u[5]*ar + u[6]*bi + u[7]*br;
      }
      __syncthreads();
    }
  }

  for (int i = tid; i < 256; i += 256) {
    Ur[i] = SR[i >> 4][i & 15];
    Ui[i] = SI[i >> 4][i & 15];
  }
  __syncthreads();

  if (tid < 192) {
    const int j = tid >> 4, a = tid & 15;
    const int typ = j >> 2;
    const int Mm = 8 >> (j & 3);
    float ax[4] = {0.f,0.f,0.f,0.f}, ay[4] = {0.f,0.f,0.f,0.f},
          az[4] = {0.f,0.f,0.f,0.f}, aw[4] = {0.f,0.f,0.f,0.f};
#pragma clang loop unroll_count(4)
    for (int k = 0; k < 16; ++k) {
      float uar = Ur[k * 16 + a], uai = Ui[k * 16 + a];
      int k2; float cR, cI;
      if (typ == 0)      { k2 = k;      float z = (k & Mm) ? -1.f : 1.f; cR = z*uar; cI = z*uai; }
      else if (typ == 1) { k2 = k ^ Mm; cR = uar; cI = uai; }
      else               { k2 = k ^ Mm; float sg = (k & Mm) ? 1.f : -1.f; cR = sg*uai; cI = -sg*uar; }
      const float* ur2 = Ur + k2 * 16;
      const float* ui2 = Ui + k2 * 16;
#pragma unroll
      for (int i = 0; i < 4; ++i) {
        ax[i] += cR * ur2[i*4+0] + cI * ui2[i*4+0];
        ay[i] += cR * ur2[i*4+1] + cI * ui2[i*4+1];
        az[i] += cR * ur2[i*4+2] + cI * ui2[i*4+2];
        aw[i] += cR * ur2[i*4+3] + cI * ui2[i*4+3];
      }
    }
    float* dst = Mout + ((c * 12 + j) * 16 + a) * 16;
#pragma unroll
    for (int i = 0; i < 4; ++i)
      ((float4*)dst)[i] = make_float4(ax[i], ay[i], az[i], aw[i]);
  }
}

// ---- K1: front: LN -> psi -> t -> QKV, 1024 blocks x 4 rows ----
__global__ __launch_bounds__(256) void k_front(const float* __restrict__ x,
    const float* __restrict__ Wp, const float* __restrict__ bp,
    const float* __restrict__ ln_g, const float* __restrict__ ln_b,
    const float* __restrict__ Mg,
    const float* __restrict__ Wq, const float* __restrict__ bq,
    const float* __restrict__ Wk, const float* __restrict__ bk,
    const float* __restrict__ Wv, const float* __restrict__ bv,
    u16* __restrict__ Qo, u16* __restrict__ Ko, u16* __restrict__ Vto) {
  const int rb = blockIdx.x;
  const int tid = threadIdx.x;
  const int w = tid >> 6, lane = tid & 63;
  __shared__ float pl[4][4];
  __shared__ float psil[4][16];
  __shared__ float tt[3][4][12];

  {
    const float* xr = x + (rb * 4 + w) * HD + lane * 8;
    float4 xa = *(const float4*)xr, xb = *(const float4*)(xr + 4);
    float acc[4];
#pragma unroll
    for (int j = 0; j < 4; ++j) {
      const float* wr = Wp + j * HD + lane * 8;
      float4 wa = *(const float4*)wr, wb = *(const float4*)(wr + 4);
      acc[j] = xa.x*wa.x + xa.y*wa.y + xa.z*wa.z + xa.w*wa.w
             + xb.x*wb.x + xb.y*wb.y + xb.z*wb.z + xb.w*wb.w;
    }
#pragma unroll
    for (int j = 0; j < 4; ++j)
#pragma unroll
      for (int off = 32; off >= 1; off >>= 1)
        acc[j] += __shfl_xor(acc[j], off);
    if (lane == 0) {
      float v0 = tanhf(acc[0] + bp[0]);
      float v1 = tanhf(acc[1] + bp[1]);
      float v2 = tanhf(acc[2] + bp[2]);
      float v3 = tanhf(acc[3] + bp[3]);
      float mu = 0.25f * (v0 + v1 + v2 + v3);
      float d0 = v0 - mu, d1 = v1 - mu, d2 = v2 - mu, d3 = v3 - mu;
      float inv = rsqrtf(0.25f * (d0*d0 + d1*d1 + d2*d2 + d3*d3) + 1e-5f);
      pl[w][0] = d0 * inv * ln_g[0] + ln_b[0];
      pl[w][1] = d1 * inv * ln_g[1] + ln_b[1];
      pl[w][2] = d2 * inv * ln_g[2] + ln_b[2];
      pl[w][3] = d3 * inv * ln_g[3] + ln_b[3];
    }
  }
  __syncthreads();

  if (tid < 4) {
    float cs[4], sn[4];
    sincosf(0.5f * pl[tid][0], &sn[0], &cs[0]);
    sincosf(0.5f * pl[tid][1], &sn[1], &cs[1]);
    sincosf(0.5f * pl[tid][2], &sn[2], &cs[2]);
    sincosf(0.5f * pl[tid][3], &sn[3], &cs[3]);
    float q01[4] = {cs[0]*cs[1], cs[0]*sn[1], sn[0]*cs[1], sn[0]*sn[1]};
    float q23[4] = {cs[2]*cs[3], cs[2]*sn[3], sn[2]*cs[3], sn[2]*sn[3]};
#pragma unroll
    for (int a = 0; a < 16; ++a) psil[tid][a] = q01[a >> 2] * q23[a & 3];
  }
  __syncthreads();

  if (tid < 144) {
    const int c = tid / 48, rem = tid - c * 48, j = rem >> 2, r = rem & 3;
    float psi[16];
#pragma unroll
    for (int a = 0; a < 16; ++a) psi[a] = psil[r][a];
    const float4* Mj = (const float4*)(Mg + (c * 12 + j) * 256);
    float y = 0.f;
#pragma unroll
    for (int a = 0; a < 16; ++a) {
      float rsum = 0.f;
#pragma unroll
      for (int i = 0; i < 4; ++i) {
        float4 m4 = Mj[a * 4 + i];
        rsum += m4.x*psi[i*4] + m4.y*psi[i*4+1] + m4.z*psi[i*4+2] + m4.w*psi[i*4+3];
      }
      y += psi[a] * rsum;
    }
    tt[c][r][j] = y;
  }
  __syncthreads();

  const int o0 = tid * 2;
  const int b = rb >> 8, ss0 = (rb & 255) * 4;
  const int h = o0 >> 6, d = o0 & 63;
#pragma unroll
  for (int c = 0; c < 3; ++c) {
    const float* W  = (c == 0) ? Wq : (c == 1) ? Wk : Wv;
    const float* bb = (c == 0) ? bq : (c == 1) ? bk : bv;
    float4 w0a = *(const float4*)(W + o0 * 12);
    float4 w0b = *(const float4*)(W + o0 * 12 + 4);
    float4 w0c = *(const float4*)(W + o0 * 12 + 8);
    float4 w1a = *(const float4*)(W + o0 * 12 + 12);
    float4 w1b = *(const float4*)(W + o0 * 12 + 16);
    float4 w1c = *(const float4*)(W + o0 * 12 + 20);
    float b0 = bb[o0], b1 = bb[o0 + 1];
    float r0[4], r1[4];
#pragma unroll
    for (int r = 0; r < 4; ++r) {
      const float* t = tt[c][r];
      r0[r] = b0 + t[0]*w0a.x + t[1]*w0a.y + t[2]*w0a.z + t[3]*w0a.w
                 + t[4]*w0b.x + t[5]*w0b.y + t[6]*w0b.z + t[7]*w0b.w
                 + t[8]*w0c.x + t[9]*w0c.y + t[10]*w0c.z + t[11]*w0c.w;
      r1[r] = b1 + t[0]*w1a.x + t[1]*w1a.y + t[2]*w1a.z + t[3]*w1a.w
                 + t[4]*w1b.x + t[5]*w1b.y + t[6]*w1b.z + t[7]*w1b.w
                 + t[8]*w1c.x + t[9]*w1c.y + t[10]*w1c.z + t[11]*w1c.w;
    }
    if (c == 0) {
      u16* qrow = Qo + ((b * HEADS + h) * SEQ + ss0) * HDD + d;
#pragma unroll
      for (int r = 0; r < 4; ++r)
        *(u32*)(qrow + r * HDD) =
            (u32)f2bf(r0[r] * QSCALE) | ((u32)f2bf(r1[r] * QSCALE) << 16);
    } else if (c == 1) {
      u16* krow = Ko + ((b * HEADS + h) * SEQ + ss0) * HDD + d;
#pragma unroll
      for (int r = 0; r < 4; ++r)
        *(u32*)(krow + r * HDD) = (u32)f2bf(r0[r]) | ((u32)f2bf(r1[r]) << 16);
    } else {
      u64 v0 = (u64)((u32)f2bf(r0[0]) | ((u32)f2bf(r0[1]) << 16)) |
               ((u64)((u32)f2bf(r0[2]) | ((u32)f2bf(r0[3]) << 16)) << 32);
      u64 v1 = (u64)((u32)f2bf(r1[0]) | ((u32)f2bf(r1[1]) << 16)) |
               ((u64)((u32)f2bf(r1[2]) | ((u32)f2bf(r1[3]) << 16)) << 32);
      *(u64*)(Vto + (b * 512 + o0) * SEQ + ss0) = v0;
      *(u64*)(Vto + (b * 512 + o0 + 1) * SEQ + ss0) = v1;
    }
  }
}

// ---------------- K2: MFMA flash attention, swapped QK^T, full-K ------------
// grid 512 (XCD-swizzled -> (qt, bh)); 4 waves; chunk 64 dbuf; 40 KB LDS.
// In-kernel normalization, bf16 output [B*S][512].
__global__ __launch_bounds__(256) void k_attn_mfma(const u16* __restrict__ Q,
    const u16* __restrict__ K, const u16* __restrict__ Vt,
    u16* __restrict__ Ob) {
  // T1 bijective XCD swizzle: 16 qt-blocks of a bh stay on one XCD's L2
  const int lin = (blockIdx.x & 7) * 64 + (blockIdx.x >> 3);
  const int bh = lin >> 4, qt = lin & 15;
  const int tid = threadIdx.x, w = tid >> 6, l = tid & 63;
  const int lr = l & 15, lh = l >> 4;

  __shared__ u16 Kl[2][64 * 64];
  __shared__ u16 Vl[2][64 * 64];
  __shared__ u16 Pl[4][16 * 64];

  const u16* Qb = Q + (bh * SEQ + qt * 64) * HDD;
  const u16* Kb = K + bh * SEQ * HDD;
  const u16* Vb = Vt + bh * HDD * SEQ;
  u16* Plw = Pl[w];

  sh8 qf[2];
#pragma unroll
  for (int kk = 0; kk < 2; ++kk)
    qf[kk] = *(const sh8*)(Qb + (w * 16 + lr) * HDD + kk * 32 + lh * 8);

  f4 oacc[4];
  float lsum = 0.f;                  // partial row-sum for q = lr
#pragma unroll
  for (int n = 0; n < 4; ++n) oacc[n] = (f4){0.f, 0.f, 0.f, 0.f};

  sh8 kreg[2], vreg[2];

#define STAGE_LOAD(ch) { \
    _Pragma("unroll") \
    for (int i = 0; i < 2; ++i) { \
      int idx = i * 256 + tid; \
      kreg[i] = *(const sh8*)(Kb + ((ch) * 64 + (idx >> 3)) * HDD + (idx & 7) * 8); \
      vreg[i] = *(const sh8*)(Vb + (idx >> 3) * SEQ + (ch) * 64 + (idx & 7) * 8); \
    } }
#define STAGE_WRITE(buf) { \
    _Pragma("unroll") \
    for (int i = 0; i < 2; ++i) { \
      int idx = i * 256 + tid; \
      *(sh8*)((char*)Kl[buf] + SWZA(idx >> 3, (idx & 7) * 16)) = kreg[i]; \
      *(sh8*)((char*)Vl[buf] + SWZA(idx >> 3, (idx & 7) * 16)) = vreg[i]; \
    } }

  STAGE_LOAD(0)
  STAGE_WRITE(0)
  __syncthreads();

  for (int it = 0; it < 16; ++it) {
    const int cur = it & 1;
    if (it < 15) STAGE_LOAD(it + 1)      // issue early; lands under compute

    // S^T = K Q^T : sacc[n][r] = S[q=lr][key = n*16 + lh*4 + r]
    f4 sacc[4];
#pragma unroll
    for (int n = 0; n < 4; ++n) sacc[n] = (f4){0.f, 0.f, 0.f, 0.f};
    __builtin_amdgcn_s_setprio(1);
#pragma unroll
    for (int kk = 0; kk < 2; ++kk) {
#pragma unroll
      for (int n = 0; n < 4; ++n) {
        sh8 kf = *(const sh8*)((const char*)Kl[cur] + SWZA(n * 16 + lr, kk * 64 + lh * 16));
        sacc[n] = mfma16(kf, qf[kk], sacc[n]);
      }
    }
    __builtin_amdgcn_s_setprio(0);

    // P = 2^S -> packed b64 LDS writes; lane-local partial sums
#pragma unroll
    for (int n = 0; n < 4; ++n) {
      float p0 = exp2f(sacc[n][0]);
      float p1 = exp2f(sacc[n][1]);
      float p2 = exp2f(sacc[n][2]);
      float p3 = exp2f(sacc[n][3]);
      lsum += (p0 + p1) + (p2 + p3);
      u32 w0 = cvt_pk_bf16(p0, p1);
      u32 w1 = cvt_pk_bf16(p2, p3);
      *(uint2*)((char*)Plw + SWZA(lr, n * 32 + lh * 8)) = make_uint2(w0, w1);
    }

    // O += P V
    __builtin_amdgcn_s_setprio(1);
#pragma unroll
    for (int kk = 0; kk < 2; ++kk) {
      sh8 pf = *(const sh8*)((const char*)Plw + SWZA(lr, kk * 64 + lh * 16));
#pragma unroll
      for (int n = 0; n < 4; ++n) {
        sh8 vf = *(const sh8*)((const char*)Vl[cur] + SWZA(n * 16 + lr, kk * 64 + lh * 16));
        oacc[n] = mfma16(pf, vf, oacc[n]);
      }
    }
    __builtin_amdgcn_s_setprio(0);

    if (it < 15) STAGE_WRITE(cur ^ 1)
    __syncthreads();
  }
#undef STAGE_LOAD
#undef STAGE_WRITE

  // total lsum for q = lr (reduce the 4 lh replicas)
  lsum += __shfl_xor(lsum, 16);
  lsum += __shfl_xor(lsum, 32);

  const int bb = bh >> 3, h = bh & 7;
#pragma unroll
  for (int r = 0; r < 4; ++r) {
    int row = qt * 64 + w * 16 + lh * 4 + r;
    float inv = 1.f / __shfl(lsum, lh * 4 + r);    // sum for q = lh*4+r
    u16* orow = Ob + (bb * SEQ + row) * HD + h * 64;
#pragma unroll
    for (int n = 0; n < 4; ++n)
      orow[n * 16 + lr] = f2bf(oacc[n][r] * inv);
  }
}

// ---- K3: out = a @ Wo^T + bo (MFMA; bf16 Wo pre-converted in k_prep) ----
__global__ __launch_bounds__(256) void k_oproj_mfma(const u16* __restrict__ A,
    const u16* __restrict__ W, const float* __restrict__ bo,
    float* __restrict__ out) {
  const int nb = blockIdx.x, ob = blockIdx.y;
  const int tid = threadIdx.x, w = tid >> 6, l = tid & 63;
  const int lr = l & 15, lh = l >> 4;
  __shared__ u16 Al[64 * 64];
  __shared__ u16 Wl[64 * 64];
  f4 acc[4];
#pragma unroll
  for (int n = 0; n < 4; ++n) acc[n] = (f4){0.f, 0.f, 0.f, 0.f};
  for (int ch = 0; ch < 8; ++ch) {
    __syncthreads();
#pragma unroll
    for (int i = 0; i < 2; ++i) {
      int idx = i * 256 + tid;
      int r = idx >> 3, c8 = idx & 7;
      *(sh8*)((char*)Al + SWZA(r, c8 * 16)) =
          *(const sh8*)(A + (nb * 64 + r) * HD + ch * 64 + c8 * 8);
      *(sh8*)((char*)Wl + SWZA(r, c8 * 16)) =
          *(const sh8*)(W + (ob * 64 + r) * HD + ch * 64 + c8 * 8);
    }
    __syncthreads();
#pragma unroll
    for (int kk = 0; kk < 2; ++kk) {
      sh8 af = *(const sh8*)((const char*)Al + SWZA(w * 16 + lr, kk * 64 + lh * 16));
#pragma unroll
      for (int n = 0; n < 4; ++n) {
        sh8 wf = *(const sh8*)((const char*)Wl + SWZA(n * 16 + lr, kk * 64 + lh * 16));
        acc[n] = mfma16(af, wf, acc[n]);
      }
    }
  }
#pragma unroll
  for (int r = 0; r < 4; ++r) {
    int row = nb * 64 + w * 16 + lh * 4 + r;
#pragma unroll
    for (int n = 0; n < 4; ++n) {
      int col = ob * 64 + n * 16 + lr;
      out[row * HD + col] = acc[n][r] + bo[col];
    }
  }
}

// ---------------- launch ----------------
extern "C" void kernel_launch(void* const* d_in, const int* in_sizes, int n_in,
                              void* d_out, int out_size, void* d_ws, size_t ws_size,
                              hipStream_t stream) {
  const float* x    = (const float*)d_in[0];
  const float* Wp   = (const float*)d_in[1];
  const float* bp   = (const float*)d_in[2];
  const float* ln_g = (const float*)d_in[3];
  const float* ln_b = (const float*)d_in[4];
  const float* qw   = (const float*)d_in[5];
  const float* qe   = (const float*)d_in[6];
  const float* qg   = (const float*)d_in[7];
  const float* qb_  = (const float*)d_in[8];
  const float* kw   = (const float*)d_in[9];
  const float* ke   = (const float*)d_in[10];
  const float* kg   = (const float*)d_in[11];
  const float* kb_  = (const float*)d_in[12];
  const float* vw   = (const float*)d_in[13];
  const float* ve   = (const float*)d_in[14];
  const float* vg   = (const float*)d_in[15];
  const float* vb_  = (const float*)d_in[16];
  const float* Wq   = (const float*)d_in[17];
  const float* bq   = (const float*)d_in[18];
  const float* Wk   = (const float*)d_in[19];
  const float* bk   = (const float*)d_in[20];
  const float* Wv   = (const float*)d_in[21];
  const float* bv   = (const float*)d_in[22];
  const float* Wo   = (const float*)d_in[23];
  const float* bo   = (const float*)d_in[24];

  float* ws   = (float*)d_ws;
  float* Mbuf = ws;                        // 9216 f
  u16* qb  = (u16*)(Mbuf + 9216);          // 32*1024*64 u16
  u16* kb  = qb + 32 * SEQ * HDD;
  u16* vtb = kb + 32 * SEQ * HDD;
  u16* ab  = vtb + 32 * SEQ * HDD;         // 4096*512 u16
  u16* wob = ab + NROWS * HD;              // 512*512 u16

  k_prep<<<11, 256, 0, stream>>>(qw, qe, qg, qb_, kw, ke, kg, kb_,
                                 vw, ve, vg, vb_, Wo, Mbuf, wob);
  k_front<<<NROWS / 4, 256, 0, stream>>>(x, Wp, bp, ln_g, ln_b, Mbuf,
                                         Wq, bq, Wk, bk, Wv, bv, qb, kb, vtb);
  k_attn_mfma<<<512, 256, 0, stream>>>(qb, kb, vtb, ab);
  dim3 go(NROWS / 64, HD / 64);
  k_oproj_mfma<<<go, 256, 0, stream>>>(ab, wob, bo, (float*)d_out);
}

// Round 16
// 71.898 us; speedup vs baseline: 1.1237x; 1.0235x over previous
//
#include <hip/hip_runtime.h>
#include <hip/hip_bf16.h>
#include <math.h>

#define NROWS 4096
#define HD 512
#define HEADS 8
#define HDD 64
#define SEQ 1024
#define QSCALE 0.18033688011112042f   // 0.125 * log2(e)

typedef unsigned short u16;
typedef unsigned int u32;
typedef unsigned long long u64;
typedef __attribute__((ext_vector_type(8))) short sh8;   // 8 bf16 (4 VGPRs)
typedef __attribute__((ext_vector_type(4))) float f4;    // MFMA accumulator

__device__ __forceinline__ f4 mfma16(sh8 a, sh8 b, f4 c) {
  return __builtin_amdgcn_mfma_f32_16x16x32_bf16(a, b, c, 0, 0, 0);
}

__device__ __forceinline__ u16 f2bf(float x) {
  union { float f; unsigned u; } v; v.f = x;
  unsigned r = v.u + 0x7fff + ((v.u >> 16) & 1);   // RNE
  return (u16)(r >> 16);
}

// packed fp32x2 -> bf16x2 (lo = first arg), 1 VALU op (T12 recipe)
__device__ __forceinline__ u32 cvt_pk_bf16(float lo, float hi) {
  u32 r;
  asm("v_cvt_pk_bf16_f32 %0, %1, %2" : "=v"(r) : "v"(lo), "v"(hi));
  return r;
}

// XOR swizzles (spread same-column b128 reads across 8 16B slots)
#define SWZA(r, cb) ((((r) * 128) + (cb)) ^ (((r) & 7) << 4))   // 128B rows
#define SWZB(r, cb) ((((r) * 256) + (cb)) ^ (((r) & 7) << 4))   // 256B rows

// ---------------- K0: prep ----------------
// blocks 0..2 : circuit -> U -> M[c][12][16][16]
// blocks 3..10: convert Wo (fp32 512x512) -> bf16 once
__global__ __launch_bounds__(256) void k_prep(
    const float* __restrict__ qw, const float* __restrict__ qe,
    const float* __restrict__ qg, const float* __restrict__ qb,
    const float* __restrict__ kw, const float* __restrict__ ke,
    const float* __restrict__ kg, const float* __restrict__ kb,
    const float* __restrict__ vw, const float* __restrict__ ve,
    const float* __restrict__ vg, const float* __restrict__ vb,
    const float* __restrict__ Wo, float* __restrict__ Mout,
    u16* __restrict__ Wob) {
  const int c = blockIdx.x;
  const int tid = threadIdx.x;

  if (c >= 3) {                        // ---- Wo conversion ----
    const int base = (c - 3) * 32768 + tid * 128;
#pragma unroll
    for (int i = 0; i < 16; ++i) {
      const float* src = Wo + base + i * 8;
      float4 f0 = *(const float4*)src;
      float4 f1 = *(const float4*)(src + 4);
      uint4 v;
      v.x = cvt_pk_bf16(f0.x, f0.y);
      v.y = cvt_pk_bf16(f0.z, f0.w);
      v.z = cvt_pk_bf16(f1.x, f1.y);
      v.w = cvt_pk_bf16(f1.z, f1.w);
      *(uint4*)(Wob + base + i * 8) = v;
    }
    return;
  }

  __shared__ float aC[32], aS[32];
  __shared__ float GT[60][8];
  __shared__ int   GM[60][2];
  __shared__ float PF[3][16][2];
  __shared__ float SR[16][17], SI[16][17];
  __shared__ float TS[16], TI[16];
  __shared__ float Ur[256], Ui[256];

  const float* w = (c == 0) ? qw : (c == 1) ? kw : vw;
  const float* e = (c == 0) ? qe : (c == 1) ? ke : ve;
  const float* g = (c == 0) ? qg : (c == 1) ? kg : vg;
  const float* b = (c == 0) ? qb : (c == 1) ? kb : vb;

  if (tid < 30) {
    float ang = (tid < 12) ? w[tid] : (tid < 24) ? e[tid - 12]
               : (tid < 27) ? g[tid - 24] : b[tid - 27];
    float s_, c_;
    sincosf(0.5f * ang, &s_, &c_);
    aC[tid] = c_; aS[tid] = s_;
  }
  __syncthreads();

  if (tid < 60) {
    int L = tid / 20, s5 = tid % 20;
    int typ, aidx, M, C;
    if (s5 < 12) {
      int q = s5 / 3; typ = s5 % 3; aidx = L * 4 + q; M = 8 >> q; C = 0;
    } else if (s5 < 16) {
      int q = s5 - 12; typ = 0; aidx = 12 + L * 4 + q;
      C = 8 >> q; M = 8 >> ((q + 1) & 3);
    } else {
      int q = s5 - 16; typ = 0; aidx = 27 + L; M = 8 >> q; C = 0;
    }
    float cc = aC[aidx], ss = aS[aidx];
    float u0r = cc, u0i = 0.f, u1r = 0.f, u1i = 0.f,
          u2r = 0.f, u2i = 0.f, u3r = cc, u3i = 0.f;
    if (typ == 0)      { u1i = -ss; u2i = -ss; }
    else if (typ == 1) { u1r = -ss; u2r = ss; }
    else               { u0i = -ss; u3i = ss; }
    GT[tid][0] = u0r; GT[tid][1] = u0i; GT[tid][2] = u1r; GT[tid][3] = u1i;
    GT[tid][4] = u2r; GT[tid][5] = u2i; GT[tid][6] = u3r; GT[tid][7] = u3i;
    GM[tid][0] = M; GM[tid][1] = C;
  }
  if (tid >= 64 && tid < 112) {
    int idx = tid - 64, L = idx >> 4, a = idx & 15;
    float cg = aC[24 + L], sg = aS[24 + L];
    float c2 = cg * cg - sg * sg, s2 = 2.f * cg * sg;
    float c3 = cg * c2 - sg * s2, s3 = cg * s2 + sg * c2;
    int u = (a ^ (a >> 1)) & 7;
    int n = (u & 1) + ((u >> 1) & 1) + ((u >> 2) & 1);
    PF[L][a][0] = (n == 0 || n == 3) ? c3 : cg;
    PF[L][a][1] = (n == 0) ? -s3 : (n == 1) ? -sg : (n == 2) ? sg : s3;
  }
  for (int i = tid; i < 256; i += 256) {
    SR[i >> 4][i & 15] = (i >> 4) == (i & 15) ? 1.f : 0.f;
    SI[i >> 4][i & 15] = 0.f;
  }
  __syncthreads();

  const int p = tid >> 4, col = tid & 15;
  for (int L = 0; L < 3; ++L) {
    for (int s5 = 0; s5 < 16; ++s5) {
      if (tid < 128) {
        int gi = L * 20 + s5;
        const float* u = GT[gi];
        int M = GM[gi][0], C = GM[gi][1];
        int lo = p & (M - 1);
        int a = ((p - lo) << 1) | lo;
        int bb = a | M;
        bool act = (C == 0) | ((a & C) != 0);
        float ar = SR[a][col], ai = SI[a][col];
        float br = SR[bb][col], bi = SI[bb][col];
        float nar = u[0]*ar - u[1]*ai + u[2]*br - u[3]*bi;
        float nai = u[0]*ai + u[1]*ar + u[2]*bi + u[3]*br;
        float nbr = u[4]*ar - u[5]*ai + u[6]*br - u[7]*bi;
        float nbi = u[4]*ai + u[5]*ar + u[6]*bi + u[7]*br;
        SR[a][col]  = act ? nar : ar;  SI[a][col]  = act ? nai : ai;
        SR[bb][col] = act ? nbr : br;  SI[bb][col] = act ? nbi : bi;
      }
      __syncthreads();
    }
    if (tid < 16) {
      float sR = 0.f, sI = 0.f;
      for (int a = 0; a < 16; ++a) { sR += SR[a][tid]; sI += SI[a][tid]; }
      TS[tid] = sR * 0.125f; TI[tid] = sI * 0.125f;
    }
    __syncthreads();
    if (tid < 128) {
      for (int k = 0; k < 2; ++k) {
        int a = 2 * p + k;
        float vr = SR[a][col] - TS[col];
        float vi = SI[a][col] - TI[col];
        float pc = PF[L][a][0], ps = PF[L][a][1];
        SR[a][col] = vr * pc - vi * ps;
        SI[a][col] = vr * ps + vi * pc;
      }
    }
    __syncthreads();
    for (int s5 = 16; s5 < 20; ++s5) {
      if (tid < 128) {
        int gi = L * 20 + s5;
        const float* u = GT[gi];
        int M = GM[gi][0];
        int lo = p & (M - 1);
        int a = ((p - lo) << 1) | lo;
        int bb = a | M;
        float ar = SR[a][col], ai = SI[a][col];
        float br = SR[bb][col], bi = SI[bb][col];
        SR[a][col]  = u[0]*ar - u[1]*ai + u[2]*br - u[3]*bi;
        SI[a][col]  = u[0]*ai + u[1]*ar + u[2]*bi + u[3]*br;
        SR[bb][col] = u[4]*ar - u[5]*ai + u[6]*br - u[7]*bi;
        SI[bb][col] = u[4]*ai + u[5]*ar + u[6]*bi + u[7]*br;
      }
      __syncthreads();
    }
  }

  for (int i = tid; i < 256; i += 256) {
    Ur[i] = SR[i >> 4][i & 15];
    Ui[i] = SI[i >> 4][i & 15];
  }
  __syncthreads();

  if (tid < 192) {
    const int j = tid >> 4, a = tid & 15;
    const int typ = j >> 2;
    const int Mm = 8 >> (j & 3);
    float ax[4] = {0.f,0.f,0.f,0.f}, ay[4] = {0.f,0.f,0.f,0.f},
          az[4] = {0.f,0.f,0.f,0.f}, aw[4] = {0.f,0.f,0.f,0.f};
#pragma clang loop unroll_count(4)
    for (int k = 0; k < 16; ++k) {
      float uar = Ur[k * 16 + a], uai = Ui[k * 16 + a];
      int k2; float cR, cI;
      if (typ == 0)      { k2 = k;      float z = (k & Mm) ? -1.f : 1.f; cR = z*uar; cI = z*uai; }
      else if (typ == 1) { k2 = k ^ Mm; cR = uar; cI = uai; }
      else               { k2 = k ^ Mm; float sg = (k & Mm) ? 1.f : -1.f; cR = sg*uai; cI = -sg*uar; }
      const float* ur2 = Ur + k2 * 16;
      const float* ui2 = Ui + k2 * 16;
#pragma unroll
      for (int i = 0; i < 4; ++i) {
        ax[i] += cR * ur2[i*4+0] + cI * ui2[i*4+0];
        ay[i] += cR * ur2[i*4+1] + cI * ui2[i*4+1];
        az[i] += cR * ur2[i*4+2] + cI * ui2[i*4+2];
        aw[i] += cR * ur2[i*4+3] + cI * ui2[i*4+3];
      }
    }
    float* dst = Mout + ((c * 12 + j) * 16 + a) * 16;
#pragma unroll
    for (int i = 0; i < 4; ++i)
      ((float4*)dst)[i] = make_float4(ax[i], ay[i], az[i], aw[i]);
  }
}

// ---- K1: front: LN -> psi -> t -> QKV, 1024 blocks x 4 rows ----
__global__ __launch_bounds__(256) void k_front(const float* __restrict__ x,
    const float* __restrict__ Wp, const float* __restrict__ bp,
    const float* __restrict__ ln_g, const float* __restrict__ ln_b,
    const float* __restrict__ Mg,
    const float* __restrict__ Wq, const float* __restrict__ bq,
    const float* __restrict__ Wk, const float* __restrict__ bk,
    const float* __restrict__ Wv, const float* __restrict__ bv,
    u16* __restrict__ Qo, u16* __restrict__ Ko, u16* __restrict__ Vto) {
  const int rb = blockIdx.x;
  const int tid = threadIdx.x;
  const int w = tid >> 6, lane = tid & 63;
  __shared__ float pl[4][4];
  __shared__ float psil[4][16];
  __shared__ float tt[3][4][12];

  {
    const float* xr = x + (rb * 4 + w) * HD + lane * 8;
    float4 xa = *(const float4*)xr, xb = *(const float4*)(xr + 4);
    float acc[4];
#pragma unroll
    for (int j = 0; j < 4; ++j) {
      const float* wr = Wp + j * HD + lane * 8;
      float4 wa = *(const float4*)wr, wb = *(const float4*)(wr + 4);
      acc[j] = xa.x*wa.x + xa.y*wa.y + xa.z*wa.z + xa.w*wa.w
             + xb.x*wb.x + xb.y*wb.y + xb.z*wb.z + xb.w*wb.w;
    }
#pragma unroll
    for (int j = 0; j < 4; ++j)
#pragma unroll
      for (int off = 32; off >= 1; off >>= 1)
        acc[j] += __shfl_xor(acc[j], off);
    if (lane == 0) {
      float v0 = tanhf(acc[0] + bp[0]);
      float v1 = tanhf(acc[1] + bp[1]);
      float v2 = tanhf(acc[2] + bp[2]);
      float v3 = tanhf(acc[3] + bp[3]);
      float mu = 0.25f * (v0 + v1 + v2 + v3);
      float d0 = v0 - mu, d1 = v1 - mu, d2 = v2 - mu, d3 = v3 - mu;
      float inv = rsqrtf(0.25f * (d0*d0 + d1*d1 + d2*d2 + d3*d3) + 1e-5f);
      pl[w][0] = d0 * inv * ln_g[0] + ln_b[0];
      pl[w][1] = d1 * inv * ln_g[1] + ln_b[1];
      pl[w][2] = d2 * inv * ln_g[2] + ln_b[2];
      pl[w][3] = d3 * inv * ln_g[3] + ln_b[3];
    }
  }
  __syncthreads();

  if (tid < 4) {
    float cs[4], sn[4];
    sincosf(0.5f * pl[tid][0], &sn[0], &cs[0]);
    sincosf(0.5f * pl[tid][1], &sn[1], &cs[1]);
    sincosf(0.5f * pl[tid][2], &sn[2], &cs[2]);
    sincosf(0.5f * pl[tid][3], &sn[3], &cs[3]);
    float q01[4] = {cs[0]*cs[1], cs[0]*sn[1], sn[0]*cs[1], sn[0]*sn[1]};
    float q23[4] = {cs[2]*cs[3], cs[2]*sn[3], sn[2]*cs[3], sn[2]*sn[3]};
#pragma unroll
    for (int a = 0; a < 16; ++a) psil[tid][a] = q01[a >> 2] * q23[a & 3];
  }
  __syncthreads();

  if (tid < 144) {
    const int c = tid / 48, rem = tid - c * 48, j = rem >> 2, r = rem & 3;
    float psi[16];
#pragma unroll
    for (int a = 0; a < 16; ++a) psi[a] = psil[r][a];
    const float4* Mj = (const float4*)(Mg + (c * 12 + j) * 256);
    float y = 0.f;
#pragma unroll
    for (int a = 0; a < 16; ++a) {
      float rsum = 0.f;
#pragma unroll
      for (int i = 0; i < 4; ++i) {
        float4 m4 = Mj[a * 4 + i];
        rsum += m4.x*psi[i*4] + m4.y*psi[i*4+1] + m4.z*psi[i*4+2] + m4.w*psi[i*4+3];
      }
      y += psi[a] * rsum;
    }
    tt[c][r][j] = y;
  }
  __syncthreads();

  const int o0 = tid * 2;
  const int b = rb >> 8, ss0 = (rb & 255) * 4;
  const int h = o0 >> 6, d = o0 & 63;
#pragma unroll
  for (int c = 0; c < 3; ++c) {
    const float* W  = (c == 0) ? Wq : (c == 1) ? Wk : Wv;
    const float* bb = (c == 0) ? bq : (c == 1) ? bk : bv;
    float4 w0a = *(const float4*)(W + o0 * 12);
    float4 w0b = *(const float4*)(W + o0 * 12 + 4);
    float4 w0c = *(const float4*)(W + o0 * 12 + 8);
    float4 w1a = *(const float4*)(W + o0 * 12 + 12);
    float4 w1b = *(const float4*)(W + o0 * 12 + 16);
    float4 w1c = *(const float4*)(W + o0 * 12 + 20);
    float b0 = bb[o0], b1 = bb[o0 + 1];
    float r0[4], r1[4];
#pragma unroll
    for (int r = 0; r < 4; ++r) {
      const float* t = tt[c][r];
      r0[r] = b0 + t[0]*w0a.x + t[1]*w0a.y + t[2]*w0a.z + t[3]*w0a.w
                 + t[4]*w0b.x + t[5]*w0b.y + t[6]*w0b.z + t[7]*w0b.w
                 + t[8]*w0c.x + t[9]*w0c.y + t[10]*w0c.z + t[11]*w0c.w;
      r1[r] = b1 + t[0]*w1a.x + t[1]*w1a.y + t[2]*w1a.z + t[3]*w1a.w
                 + t[4]*w1b.x + t[5]*w1b.y + t[6]*w1b.z + t[7]*w1b.w
                 + t[8]*w1c.x + t[9]*w1c.y + t[10]*w1c.z + t[11]*w1c.w;
    }
    if (c == 0) {
      u16* qrow = Qo + ((b * HEADS + h) * SEQ + ss0) * HDD + d;
#pragma unroll
      for (int r = 0; r < 4; ++r)
        *(u32*)(qrow + r * HDD) =
            (u32)f2bf(r0[r] * QSCALE) | ((u32)f2bf(r1[r] * QSCALE) << 16);
    } else if (c == 1) {
      u16* krow = Ko + ((b * HEADS + h) * SEQ + ss0) * HDD + d;
#pragma unroll
      for (int r = 0; r < 4; ++r)
        *(u32*)(krow + r * HDD) = (u32)f2bf(r0[r]) | ((u32)f2bf(r1[r]) << 16);
    } else {
      u64 v0 = (u64)((u32)f2bf(r0[0]) | ((u32)f2bf(r0[1]) << 16)) |
               ((u64)((u32)f2bf(r0[2]) | ((u32)f2bf(r0[3]) << 16)) << 32);
      u64 v1 = (u64)((u32)f2bf(r1[0]) | ((u32)f2bf(r1[1]) << 16)) |
               ((u64)((u32)f2bf(r1[2]) | ((u32)f2bf(r1[3]) << 16)) << 32);
      *(u64*)(Vto + (b * 512 + o0) * SEQ + ss0) = v0;
      *(u64*)(Vto + (b * 512 + o0 + 1) * SEQ + ss0) = v1;
    }
  }
}

// ---------------- K2: MFMA flash attention, swapped QK^T, chunk 128 ----------
// grid 512 (XCD-swizzled -> (qt, bh)); 4 waves; KV chunk 128 dbuf; 80 KB LDS.
// 8 iterations (half the barriers of chunk-64). In-kernel normalization.
__global__ __launch_bounds__(256) void k_attn_mfma(const u16* __restrict__ Q,
    const u16* __restrict__ K, const u16* __restrict__ Vt,
    u16* __restrict__ Ob) {
  // T1 bijective XCD swizzle: 16 qt-blocks of a bh stay on one XCD's L2
  const int lin = (blockIdx.x & 7) * 64 + (blockIdx.x >> 3);
  const int bh = lin >> 4, qt = lin & 15;
  const int tid = threadIdx.x, w = tid >> 6, l = tid & 63;
  const int lr = l & 15, lh = l >> 4;

  __shared__ u16 Kl[2][128 * 64];    // [key][d]   128B rows, SWZA  (32 KB)
  __shared__ u16 Vl[2][64 * 128];    // [d][key]   256B rows, SWZB  (32 KB)
  __shared__ u16 Pl[4][16 * 128];    // per-wave P [q][key] SWZB    (16 KB)

  const u16* Qb = Q + (bh * SEQ + qt * 64) * HDD;
  const u16* Kb = K + bh * SEQ * HDD;
  const u16* Vb = Vt + bh * HDD * SEQ;
  u16* Plw = Pl[w];

  sh8 qf[2];
#pragma unroll
  for (int kk = 0; kk < 2; ++kk)
    qf[kk] = *(const sh8*)(Qb + (w * 16 + lr) * HDD + kk * 32 + lh * 8);

  f4 oacc[4];
  float lsum = 0.f;                  // partial row-sum for q = lr
#pragma unroll
  for (int n = 0; n < 4; ++n) oacc[n] = (f4){0.f, 0.f, 0.f, 0.f};

  sh8 kreg[4], vreg[4];

#define STAGE_LOAD(ch) { \
    _Pragma("unroll") \
    for (int i = 0; i < 4; ++i) { \
      int idx = i * 256 + tid; \
      kreg[i] = *(const sh8*)(Kb + ((ch) * 128 + (idx >> 3)) * HDD + (idx & 7) * 8); \
      vreg[i] = *(const sh8*)(Vb + (idx >> 4) * SEQ + (ch) * 128 + (idx & 15) * 8); \
    } }
#define STAGE_WRITE(buf) { \
    _Pragma("unroll") \
    for (int i = 0; i < 4; ++i) { \
      int idx = i * 256 + tid; \
      *(sh8*)((char*)Kl[buf] + SWZA(idx >> 3, (idx & 7) * 16)) = kreg[i]; \
      *(sh8*)((char*)Vl[buf] + SWZB(idx >> 4, (idx & 15) * 16)) = vreg[i]; \
    } }

  STAGE_LOAD(0)
  STAGE_WRITE(0)
  __syncthreads();

  for (int it = 0; it < 8; ++it) {
    const int cur = it & 1;
    if (it < 7) STAGE_LOAD(it + 1)       // issue early; lands under compute

    // S^T = K Q^T : sacc[n][r] = S[q=lr][key = n*16 + lh*4 + r]
    f4 sacc[8];
#pragma unroll
    for (int n = 0; n < 8; ++n) sacc[n] = (f4){0.f, 0.f, 0.f, 0.f};
    __builtin_amdgcn_s_setprio(1);
#pragma unroll
    for (int kk = 0; kk < 2; ++kk) {
#pragma unroll
      for (int n = 0; n < 8; ++n) {
        sh8 kf = *(const sh8*)((const char*)Kl[cur] + SWZA(n * 16 + lr, kk * 64 + lh * 16));
        sacc[n] = mfma16(kf, qf[kk], sacc[n]);
      }
    }
    __builtin_amdgcn_s_setprio(0);

    // P = 2^S -> packed b64 LDS writes; lane-local partial sums
#pragma unroll
    for (int n = 0; n < 8; ++n) {
      float p0 = exp2f(sacc[n][0]);
      float p1 = exp2f(sacc[n][1]);
      float p2 = exp2f(sacc[n][2]);
      float p3 = exp2f(sacc[n][3]);
      lsum += (p0 + p1) + (p2 + p3);
      u32 w0 = cvt_pk_bf16(p0, p1);
      u32 w1 = cvt_pk_bf16(p2, p3);
      *(uint2*)((char*)Plw + SWZB(lr, n * 32 + lh * 8)) = make_uint2(w0, w1);
    }

    // O += P V
    __builtin_amdgcn_s_setprio(1);
#pragma unroll
    for (int kk = 0; kk < 4; ++kk) {
      sh8 pf = *(const sh8*)((const char*)Plw + SWZB(lr, kk * 64 + lh * 16));
#pragma unroll
      for (int n = 0; n < 4; ++n) {
        sh8 vf = *(const sh8*)((const char*)Vl[cur] + SWZB(n * 16 + lr, kk * 64 + lh * 16));
        oacc[n] = mfma16(pf, vf, oacc[n]);
      }
    }
    __builtin_amdgcn_s_setprio(0);

    if (it < 7) STAGE_WRITE(cur ^ 1)
    __syncthreads();
  }
#undef STAGE_LOAD
#undef STAGE_WRITE

  // total lsum for q = lr (reduce the 4 lh replicas)
  lsum += __shfl_xor(lsum, 16);
  lsum += __shfl_xor(lsum, 32);

  const int bb = bh >> 3, h = bh & 7;
#pragma unroll
  for (int r = 0; r < 4; ++r) {
    int row = qt * 64 + w * 16 + lh * 4 + r;
    float inv = 1.f / __shfl(lsum, lh * 4 + r);    // sum for q = lh*4+r
    u16* orow = Ob + (bb * SEQ + row) * HD + h * 64;
#pragma unroll
    for (int n = 0; n < 4; ++n)
      orow[n * 16 + lr] = f2bf(oacc[n][r] * inv);
  }
}

// ---- K3: out = a @ Wo^T + bo (MFMA; bf16 Wo pre-converted in k_prep) ----
__global__ __launch_bounds__(256) void k_oproj_mfma(const u16* __restrict__ A,
    const u16* __restrict__ W, const float* __restrict__ bo,
    float* __restrict__ out) {
  const int nb = blockIdx.x, ob = blockIdx.y;
  const int tid = threadIdx.x, w = tid >> 6, l = tid & 63;
  const int lr = l & 15, lh = l >> 4;
  __shared__ u16 Al[64 * 64];
  __shared__ u16 Wl[64 * 64];
  f4 acc[4];
#pragma unroll
  for (int n = 0; n < 4; ++n) acc[n] = (f4){0.f, 0.f, 0.f, 0.f};
  for (int ch = 0; ch < 8; ++ch) {
    __syncthreads();
#pragma unroll
    for (int i = 0; i < 2; ++i) {
      int idx = i * 256 + tid;
      int r = idx >> 3, c8 = idx & 7;
      *(sh8*)((char*)Al + SWZA(r, c8 * 16)) =
          *(const sh8*)(A + (nb * 64 + r) * HD + ch * 64 + c8 * 8);
      *(sh8*)((char*)Wl + SWZA(r, c8 * 16)) =
          *(const sh8*)(W + (ob * 64 + r) * HD + ch * 64 + c8 * 8);
    }
    __syncthreads();
#pragma unroll
    for (int kk = 0; kk < 2; ++kk) {
      sh8 af = *(const sh8*)((const char*)Al + SWZA(w * 16 + lr, kk * 64 + lh * 16));
#pragma unroll
      for (int n = 0; n < 4; ++n) {
        sh8 wf = *(const sh8*)((const char*)Wl + SWZA(n * 16 + lr, kk * 64 + lh * 16));
        acc[n] = mfma16(af, wf, acc[n]);
      }
    }
  }
#pragma unroll
  for (int r = 0; r < 4; ++r) {
    int row = nb * 64 + w * 16 + lh * 4 + r;
#pragma unroll
    for (int n = 0; n < 4; ++n) {
      int col = ob * 64 + n * 16 + lr;
      out[row * HD + col] = acc[n][r] + bo[col];
    }
  }
}

// ---------------- launch ----------------
extern "C" void kernel_launch(void* const* d_in, const int* in_sizes, int n_in,
                              void* d_out, int out_size, void* d_ws, size_t ws_size,
                              hipStream_t stream) {
  const float* x    = (const float*)d_in[0];
  const float* Wp   = (const float*)d_in[1];
  const float* bp   = (const float*)d_in[2];
  const float* ln_g = (const float*)d_in[3];
  const float* ln_b = (const float*)d_in[4];
  const float* qw   = (const float*)d_in[5];
  const float* qe   = (const float*)d_in[6];
  const float* qg   = (const float*)d_in[7];
  const float* qb_  = (const float*)d_in[8];
  const float* kw   = (const float*)d_in[9];
  const float* ke   = (const float*)d_in[10];
  const float* kg   = (const float*)d_in[11];
  const float* kb_  = (const float*)d_in[12];
  const float* vw   = (const float*)d_in[13];
  const float* ve   = (const float*)d_in[14];
  const float* vg   = (const float*)d_in[15];
  const float* vb_  = (const float*)d_in[16];
  const float* Wq   = (const float*)d_in[17];
  const float* bq   = (const float*)d_in[18];
  const float* Wk   = (const float*)d_in[19];
  const float* bk   = (const float*)d_in[20];
  const float* Wv   = (const float*)d_in[21];
  const float* bv   = (const float*)d_in[22];
  const float* Wo   = (const float*)d_in[23];
  const float* bo   = (const float*)d_in[24];

  float* ws   = (float*)d_ws;
  float* Mbuf = ws;                        // 9216 f
  u16* qb  = (u16*)(Mbuf + 9216);          // 32*1024*64 u16
  u16* kb  = qb + 32 * SEQ * HDD;
  u16* vtb = kb + 32 * SEQ * HDD;
  u16* ab  = vtb + 32 * SEQ * HDD;         // 4096*512 u16
  u16* wob = ab + NROWS * HD;              // 512*512 u16

  k_prep<<<11, 256, 0, stream>>>(qw, qe, qg, qb_, kw, ke, kg, kb_,
                                 vw, ve, vg, vb_, Wo, Mbuf, wob);
  k_front<<<NROWS / 4, 256, 0, stream>>>(x, Wp, bp, ln_g, ln_b, Mbuf,
                                         Wq, bq, Wk, bk, Wv, bv, qb, kb, vtb);
  k_attn_mfma<<<512, 256, 0, stream>>>(qb, kb, vtb, ab);
  dim3 go(NROWS / 64, HD / 64);
  k_oproj_mfma<<<go, 256, 0, stream>>>(ab, wob, bo, (float*)d_out);
}

// Round 17
// 70.856 us; speedup vs baseline: 1.1402x; 1.0147x over previous
//
#include <hip/hip_runtime.h>
#include <hip/hip_bf16.h>
#include <math.h>

#define NROWS 4096
#define HD 512
#define HEADS 8
#define HDD 64
#define SEQ 1024
#define QSCALE 0.18033688011112042f   // 0.125 * log2(e)

typedef unsigned short u16;
typedef unsigned int u32;
typedef unsigned long long u64;
typedef __attribute__((ext_vector_type(8))) short sh8;   // 8 bf16 (4 VGPRs)
typedef __attribute__((ext_vector_type(4))) float f4;    // MFMA accumulator

__device__ __forceinline__ f4 mfma16(sh8 a, sh8 b, f4 c) {
  return __builtin_amdgcn_mfma_f32_16x16x32_bf16(a, b, c, 0, 0, 0);
}

__device__ __forceinline__ u16 f2bf(float x) {
  union { float f; unsigned u; } v; v.f = x;
  unsigned r = v.u + 0x7fff + ((v.u >> 16) & 1);   // RNE
  return (u16)(r >> 16);
}

// packed fp32x2 -> bf16x2 (lo = first arg), 1 VALU op (T12 recipe)
__device__ __forceinline__ u32 cvt_pk_bf16(float lo, float hi) {
  u32 r;
  asm("v_cvt_pk_bf16_f32 %0, %1, %2" : "=v"(r) : "v"(lo), "v"(hi));
  return r;
}

// XOR swizzles (spread same-column b128 reads across 8 16B slots)
#define SWZA(r, cb) ((((r) * 128) + (cb)) ^ (((r) & 7) << 4))   // 128B rows
#define SWZB(r, cb) ((((r) * 256) + (cb)) ^ (((r) & 7) << 4))   // 256B rows

// ---------------- K0: prep ----------------
// blocks 0..2 : circuit -> U -> M[c][12][16][16]
// blocks 3..10: convert Wo (fp32 512x512) -> bf16 once
__global__ __launch_bounds__(256) void k_prep(
    const float* __restrict__ qw, const float* __restrict__ qe,
    const float* __restrict__ qg, const float* __restrict__ qb,
    const float* __restrict__ kw, const float* __restrict__ ke,
    const float* __restrict__ kg, const float* __restrict__ kb,
    const float* __restrict__ vw, const float* __restrict__ ve,
    const float* __restrict__ vg, const float* __restrict__ vb,
    const float* __restrict__ Wo, float* __restrict__ Mout,
    u16* __restrict__ Wob) {
  const int c = blockIdx.x;
  const int tid = threadIdx.x;

  if (c >= 3) {                        // ---- Wo conversion ----
    const int base = (c - 3) * 32768 + tid * 128;
#pragma unroll
    for (int i = 0; i < 16; ++i) {
      const float* src = Wo + base + i * 8;
      float4 f0 = *(const float4*)src;
      float4 f1 = *(const float4*)(src + 4);
      uint4 v;
      v.x = cvt_pk_bf16(f0.x, f0.y);
      v.y = cvt_pk_bf16(f0.z, f0.w);
      v.z = cvt_pk_bf16(f1.x, f1.y);
      v.w = cvt_pk_bf16(f1.z, f1.w);
      *(uint4*)(Wob + base + i * 8) = v;
    }
    return;
  }

  __shared__ float aC[32], aS[32];
  __shared__ float GT[60][8];
  __shared__ int   GM[60][2];
  __shared__ float PF[3][16][2];
  __shared__ float SR[16][17], SI[16][17];
  __shared__ float TS[16], TI[16];
  __shared__ float Ur[256], Ui[256];

  const float* w = (c == 0) ? qw : (c == 1) ? kw : vw;
  const float* e = (c == 0) ? qe : (c == 1) ? ke : ve;
  const float* g = (c == 0) ? qg : (c == 1) ? kg : vg;
  const float* b = (c == 0) ? qb : (c == 1) ? kb : vb;

  if (tid < 30) {
    float ang = (tid < 12) ? w[tid] : (tid < 24) ? e[tid - 12]
               : (tid < 27) ? g[tid - 24] : b[tid - 27];
    float s_, c_;
    sincosf(0.5f * ang, &s_, &c_);
    aC[tid] = c_; aS[tid] = s_;
  }
  __syncthreads();

  if (tid < 60) {
    int L = tid / 20, s5 = tid % 20;
    int typ, aidx, M, C;
    if (s5 < 12) {
      int q = s5 / 3; typ = s5 % 3; aidx = L * 4 + q; M = 8 >> q; C = 0;
    } else if (s5 < 16) {
      int q = s5 - 12; typ = 0; aidx = 12 + L * 4 + q;
      C = 8 >> q; M = 8 >> ((q + 1) & 3);
    } else {
      int q = s5 - 16; typ = 0; aidx = 27 + L; M = 8 >> q; C = 0;
    }
    float cc = aC[aidx], ss = aS[aidx];
    float u0r = cc, u0i = 0.f, u1r = 0.f, u1i = 0.f,
          u2r = 0.f, u2i = 0.f, u3r = cc, u3i = 0.f;
    if (typ == 0)      { u1i = -ss; u2i = -ss; }
    else if (typ == 1) { u1r = -ss; u2r = ss; }
    else               { u0i = -ss; u3i = ss; }
    GT[tid][0] = u0r; GT[tid][1] = u0i; GT[tid][2] = u1r; GT[tid][3] = u1i;
    GT[tid][4] = u2r; GT[tid][5] = u2i; GT[tid][6] = u3r; GT[tid][7] = u3i;
    GM[tid][0] = M; GM[tid][1] = C;
  }
  if (tid >= 64 && tid < 112) {
    int idx = tid - 64, L = idx >> 4, a = idx & 15;
    float cg = aC[24 + L], sg = aS[24 + L];
    float c2 = cg * cg - sg * sg, s2 = 2.f * cg * sg;
    float c3 = cg * c2 - sg * s2, s3 = cg * s2 + sg * c2;
    int u = (a ^ (a >> 1)) & 7;
    int n = (u & 1) + ((u >> 1) & 1) + ((u >> 2) & 1);
    PF[L][a][0] = (n == 0 || n == 3) ? c3 : cg;
    PF[L][a][1] = (n == 0) ? -s3 : (n == 1) ? -sg : (n == 2) ? sg : s3;
  }
  for (int i = tid; i < 256; i += 256) {
    SR[i >> 4][i & 15] = (i >> 4) == (i & 15) ? 1.f : 0.f;
    SI[i >> 4][i & 15] = 0.f;
  }
  __syncthreads();

  const int p = tid >> 4, col = tid & 15;
  for (int L = 0; L < 3; ++L) {
    for (int s5 = 0; s5 < 16; ++s5) {
      if (tid < 128) {
        int gi = L * 20 + s5;
        const float* u = GT[gi];
        int M = GM[gi][0], C = GM[gi][1];
        int lo = p & (M - 1);
        int a = ((p - lo) << 1) | lo;
        int bb = a | M;
        bool act = (C == 0) | ((a & C) != 0);
        float ar = SR[a][col], ai = SI[a][col];
        float br = SR[bb][col], bi = SI[bb][col];
        float nar = u[0]*ar - u[1]*ai + u[2]*br - u[3]*bi;
        float nai = u[0]*ai + u[1]*ar + u[2]*bi + u[3]*br;
        float nbr = u[4]*ar - u[5]*ai + u[6]*br - u[7]*bi;
        float nbi = u[4]*ai + u[5]*ar + u[6]*bi + u[7]*br;
        SR[a][col]  = act ? nar : ar;  SI[a][col]  = act ? nai : ai;
        SR[bb][col] = act ? nbr : br;  SI[bb][col] = act ? nbi : bi;
      }
      __syncthreads();
    }
    if (tid < 16) {
      float sR = 0.f, sI = 0.f;
      for (int a = 0; a < 16; ++a) { sR += SR[a][tid]; sI += SI[a][tid]; }
      TS[tid] = sR * 0.125f; TI[tid] = sI * 0.125f;
    }
    __syncthreads();
    if (tid < 128) {
      for (int k = 0; k < 2; ++k) {
        int a = 2 * p + k;
        float vr = SR[a][col] - TS[col];
        float vi = SI[a][col] - TI[col];
        float pc = PF[L][a][0], ps = PF[L][a][1];
        SR[a][col] = vr * pc - vi * ps;
        SI[a][col] = vr * ps + vi * pc;
      }
    }
    __syncthreads();
    for (int s5 = 16; s5 < 20; ++s5) {
      if (tid < 128) {
        int gi = L * 20 + s5;
        const float* u = GT[gi];
        int M = GM[gi][0];
        int lo = p & (M - 1);
        int a = ((p - lo) << 1) | lo;
        int bb = a | M;
        float ar = SR[a][col], ai = SI[a][col];
        float br = SR[bb][col], bi = SI[bb][col];
        SR[a][col]  = u[0]*ar - u[1]*ai + u[2]*br - u[3]*bi;
        SI[a][col]  = u[0]*ai + u[1]*ar + u[2]*bi + u[3]*br;
        SR[bb][col] = u[4]*ar - u[5]*ai + u[6]*br - u[7]*bi;
        SI[bb][col] = u[4]*ai + u[5]*ar + u[6]*bi + u[7]*br;
      }
      __syncthreads();
    }
  }

  for (int i = tid; i < 256; i += 256) {
    Ur[i] = SR[i >> 4][i & 15];
    Ui[i] = SI[i >> 4][i & 15];
  }
  __syncthreads();

  if (tid < 192) {
    const int j = tid >> 4, a = tid & 15;
    const int typ = j >> 2;
    const int Mm = 8 >> (j & 3);
    float ax[4] = {0.f,0.f,0.f,0.f}, ay[4] = {0.f,0.f,0.f,0.f},
          az[4] = {0.f,0.f,0.f,0.f}, aw[4] = {0.f,0.f,0.f,0.f};
#pragma clang loop unroll_count(4)
    for (int k = 0; k < 16; ++k) {
      float uar = Ur[k * 16 + a], uai = Ui[k * 16 + a];
      int k2; float cR, cI;
      if (typ == 0)      { k2 = k;      float z = (k & Mm) ? -1.f : 1.f; cR = z*uar; cI = z*uai; }
      else if (typ == 1) { k2 = k ^ Mm; cR = uar; cI = uai; }
      else               { k2 = k ^ Mm; float sg = (k & Mm) ? 1.f : -1.f; cR = sg*uai; cI = -sg*uar; }
      const float* ur2 = Ur + k2 * 16;
      const float* ui2 = Ui + k2 * 16;
#pragma unroll
      for (int i = 0; i < 4; ++i) {
        ax[i] += cR * ur2[i*4+0] + cI * ui2[i*4+0];
        ay[i] += cR * ur2[i*4+1] + cI * ui2[i*4+1];
        az[i] += cR * ur2[i*4+2] + cI * ui2[i*4+2];
        aw[i] += cR * ur2[i*4+3] + cI * ui2[i*4+3];
      }
    }
    float* dst = Mout + ((c * 12 + j) * 16 + a) * 16;
#pragma unroll
    for (int i = 0; i < 4; ++i)
      ((float4*)dst)[i] = make_float4(ax[i], ay[i], az[i], aw[i]);
  }
}

// ---- K1: front: LN -> psi -> t -> QKV, 1024 blocks x 4 rows ----
__global__ __launch_bounds__(256) void k_front(const float* __restrict__ x,
    const float* __restrict__ Wp, const float* __restrict__ bp,
    const float* __restrict__ ln_g, const float* __restrict__ ln_b,
    const float* __restrict__ Mg,
    const float* __restrict__ Wq, const float* __restrict__ bq,
    const float* __restrict__ Wk, const float* __restrict__ bk,
    const float* __restrict__ Wv, const float* __restrict__ bv,
    u16* __restrict__ Qo, u16* __restrict__ Ko, u16* __restrict__ Vto) {
  const int rb = blockIdx.x;
  const int tid = threadIdx.x;
  const int w = tid >> 6, lane = tid & 63;
  __shared__ float pl[4][4];
  __shared__ float psil[4][16];
  __shared__ float tt[3][4][12];

  {
    const float* xr = x + (rb * 4 + w) * HD + lane * 8;
    float4 xa = *(const float4*)xr, xb = *(const float4*)(xr + 4);
    float acc[4];
#pragma unroll
    for (int j = 0; j < 4; ++j) {
      const float* wr = Wp + j * HD + lane * 8;
      float4 wa = *(const float4*)wr, wb = *(const float4*)(wr + 4);
      acc[j] = xa.x*wa.x + xa.y*wa.y + xa.z*wa.z + xa.w*wa.w
             + xb.x*wb.x + xb.y*wb.y + xb.z*wb.z + xb.w*wb.w;
    }
#pragma unroll
    for (int j = 0; j < 4; ++j)
#pragma unroll
      for (int off = 32; off >= 1; off >>= 1)
        acc[j] += __shfl_xor(acc[j], off);
    if (lane == 0) {
      float v0 = tanhf(acc[0] + bp[0]);
      float v1 = tanhf(acc[1] + bp[1]);
      float v2 = tanhf(acc[2] + bp[2]);
      float v3 = tanhf(acc[3] + bp[3]);
      float mu = 0.25f * (v0 + v1 + v2 + v3);
      float d0 = v0 - mu, d1 = v1 - mu, d2 = v2 - mu, d3 = v3 - mu;
      float inv = rsqrtf(0.25f * (d0*d0 + d1*d1 + d2*d2 + d3*d3) + 1e-5f);
      pl[w][0] = d0 * inv * ln_g[0] + ln_b[0];
      pl[w][1] = d1 * inv * ln_g[1] + ln_b[1];
      pl[w][2] = d2 * inv * ln_g[2] + ln_b[2];
      pl[w][3] = d3 * inv * ln_g[3] + ln_b[3];
    }
  }
  __syncthreads();

  if (tid < 4) {
    float cs[4], sn[4];
    sincosf(0.5f * pl[tid][0], &sn[0], &cs[0]);
    sincosf(0.5f * pl[tid][1], &sn[1], &cs[1]);
    sincosf(0.5f * pl[tid][2], &sn[2], &cs[2]);
    sincosf(0.5f * pl[tid][3], &sn[3], &cs[3]);
    float q01[4] = {cs[0]*cs[1], cs[0]*sn[1], sn[0]*cs[1], sn[0]*sn[1]};
    float q23[4] = {cs[2]*cs[3], cs[2]*sn[3], sn[2]*cs[3], sn[2]*sn[3]};
#pragma unroll
    for (int a = 0; a < 16; ++a) psil[tid][a] = q01[a >> 2] * q23[a & 3];
  }
  __syncthreads();

  if (tid < 144) {
    const int c = tid / 48, rem = tid - c * 48, j = rem >> 2, r = rem & 3;
    float psi[16];
#pragma unroll
    for (int a = 0; a < 16; ++a) psi[a] = psil[r][a];
    const float4* Mj = (const float4*)(Mg + (c * 12 + j) * 256);
    float y = 0.f;
#pragma unroll
    for (int a = 0; a < 16; ++a) {
      float rsum = 0.f;
#pragma unroll
      for (int i = 0; i < 4; ++i) {
        float4 m4 = Mj[a * 4 + i];
        rsum += m4.x*psi[i*4] + m4.y*psi[i*4+1] + m4.z*psi[i*4+2] + m4.w*psi[i*4+3];
      }
      y += psi[a] * rsum;
    }
    tt[c][r][j] = y;
  }
  __syncthreads();

  const int o0 = tid * 2;
  const int b = rb >> 8, ss0 = (rb & 255) * 4;
  const int h = o0 >> 6, d = o0 & 63;
#pragma unroll
  for (int c = 0; c < 3; ++c) {
    const float* W  = (c == 0) ? Wq : (c == 1) ? Wk : Wv;
    const float* bb = (c == 0) ? bq : (c == 1) ? bk : bv;
    float4 w0a = *(const float4*)(W + o0 * 12);
    float4 w0b = *(const float4*)(W + o0 * 12 + 4);
    float4 w0c = *(const float4*)(W + o0 * 12 + 8);
    float4 w1a = *(const float4*)(W + o0 * 12 + 12);
    float4 w1b = *(const float4*)(W + o0 * 12 + 16);
    float4 w1c = *(const float4*)(W + o0 * 12 + 20);
    float b0 = bb[o0], b1 = bb[o0 + 1];
    float r0[4], r1[4];
#pragma unroll
    for (int r = 0; r < 4; ++r) {
      const float* t = tt[c][r];
      r0[r] = b0 + t[0]*w0a.x + t[1]*w0a.y + t[2]*w0a.z + t[3]*w0a.w
                 + t[4]*w0b.x + t[5]*w0b.y + t[6]*w0b.z + t[7]*w0b.w
                 + t[8]*w0c.x + t[9]*w0c.y + t[10]*w0c.z + t[11]*w0c.w;
      r1[r] = b1 + t[0]*w1a.x + t[1]*w1a.y + t[2]*w1a.z + t[3]*w1a.w
                 + t[4]*w1b.x + t[5]*w1b.y + t[6]*w1b.z + t[7]*w1b.w
                 + t[8]*w1c.x + t[9]*w1c.y + t[10]*w1c.z + t[11]*w1c.w;
    }
    if (c == 0) {
      u16* qrow = Qo + ((b * HEADS + h) * SEQ + ss0) * HDD + d;
#pragma unroll
      for (int r = 0; r < 4; ++r)
        *(u32*)(qrow + r * HDD) =
            (u32)f2bf(r0[r] * QSCALE) | ((u32)f2bf(r1[r] * QSCALE) << 16);
    } else if (c == 1) {
      u16* krow = Ko + ((b * HEADS + h) * SEQ + ss0) * HDD + d;
#pragma unroll
      for (int r = 0; r < 4; ++r)
        *(u32*)(krow + r * HDD) = (u32)f2bf(r0[r]) | ((u32)f2bf(r1[r]) << 16);
    } else {
      u64 v0 = (u64)((u32)f2bf(r0[0]) | ((u32)f2bf(r0[1]) << 16)) |
               ((u64)((u32)f2bf(r0[2]) | ((u32)f2bf(r0[3]) << 16)) << 32);
      u64 v1 = (u64)((u32)f2bf(r1[0]) | ((u32)f2bf(r1[1]) << 16)) |
               ((u64)((u32)f2bf(r1[2]) | ((u32)f2bf(r1[3]) << 16)) << 32);
      *(u64*)(Vto + (b * 512 + o0) * SEQ + ss0) = v0;
      *(u64*)(Vto + (b * 512 + o0 + 1) * SEQ + ss0) = v1;
    }
  }
}

// ------- K2: MFMA flash attention, swapped QK^T, q-tile 128, 8 waves --------
// grid 256 (XCD-swizzled -> (qt 0..7, bh 0..31)); 512 thr; chunk 128 dbuf;
// 96 KB LDS; halves L2 staging traffic + barrier-iterations vs q-tile 64.
__global__ __launch_bounds__(512) void k_attn_mfma(const u16* __restrict__ Q,
    const u16* __restrict__ K, const u16* __restrict__ Vt,
    u16* __restrict__ Ob) {
  // T1 bijective XCD swizzle (grid 256, cpx=32): 8 qt of a bh share an XCD L2
  const int lin = (blockIdx.x & 7) * 32 + (blockIdx.x >> 3);
  const int bh = lin >> 3, qt = lin & 7;
  const int tid = threadIdx.x, w = tid >> 6, l = tid & 63;
  const int lr = l & 15, lh = l >> 4;

  __shared__ u16 Kl[2][128 * 64];    // [key][d]   128B rows, SWZA  (32 KB)
  __shared__ u16 Vl[2][64 * 128];    // [d][key]   256B rows, SWZB  (32 KB)
  __shared__ u16 Pl[8][16 * 128];    // per-wave P [q][key] SWZB    (32 KB)

  const u16* Qb = Q + (bh * SEQ + qt * 128) * HDD;
  const u16* Kb = K + bh * SEQ * HDD;
  const u16* Vb = Vt + bh * HDD * SEQ;
  u16* Plw = Pl[w];

  sh8 qf[2];
#pragma unroll
  for (int kk = 0; kk < 2; ++kk)
    qf[kk] = *(const sh8*)(Qb + (w * 16 + lr) * HDD + kk * 32 + lh * 8);

  f4 oacc[4];
  float lsum = 0.f;                  // partial row-sum for q = lr
#pragma unroll
  for (int n = 0; n < 4; ++n) oacc[n] = (f4){0.f, 0.f, 0.f, 0.f};

  sh8 kreg[2], vreg[2];

#define STAGE_LOAD(ch) { \
    _Pragma("unroll") \
    for (int i = 0; i < 2; ++i) { \
      int idx = i * 512 + tid; \
      kreg[i] = *(const sh8*)(Kb + ((ch) * 128 + (idx >> 3)) * HDD + (idx & 7) * 8); \
      vreg[i] = *(const sh8*)(Vb + (idx >> 4) * SEQ + (ch) * 128 + (idx & 15) * 8); \
    } }
#define STAGE_WRITE(buf) { \
    _Pragma("unroll") \
    for (int i = 0; i < 2; ++i) { \
      int idx = i * 512 + tid; \
      *(sh8*)((char*)Kl[buf] + SWZA(idx >> 3, (idx & 7) * 16)) = kreg[i]; \
      *(sh8*)((char*)Vl[buf] + SWZB(idx >> 4, (idx & 15) * 16)) = vreg[i]; \
    } }

  STAGE_LOAD(0)
  STAGE_WRITE(0)
  __syncthreads();

  for (int it = 0; it < 8; ++it) {
    const int cur = it & 1;
    if (it < 7) STAGE_LOAD(it + 1)       // issue early; lands under compute

    // S^T = K Q^T : sacc[n][r] = S[q=lr][key = n*16 + lh*4 + r]
    f4 sacc[8];
#pragma unroll
    for (int n = 0; n < 8; ++n) sacc[n] = (f4){0.f, 0.f, 0.f, 0.f};
    __builtin_amdgcn_s_setprio(1);
#pragma unroll
    for (int kk = 0; kk < 2; ++kk) {
#pragma unroll
      for (int n = 0; n < 8; ++n) {
        sh8 kf = *(const sh8*)((const char*)Kl[cur] + SWZA(n * 16 + lr, kk * 64 + lh * 16));
        sacc[n] = mfma16(kf, qf[kk], sacc[n]);
      }
    }
    __builtin_amdgcn_s_setprio(0);

    // P = 2^S -> packed b64 LDS writes; lane-local partial sums
#pragma unroll
    for (int n = 0; n < 8; ++n) {
      float p0 = exp2f(sacc[n][0]);
      float p1 = exp2f(sacc[n][1]);
      float p2 = exp2f(sacc[n][2]);
      float p3 = exp2f(sacc[n][3]);
      lsum += (p0 + p1) + (p2 + p3);
      u32 w0 = cvt_pk_bf16(p0, p1);
      u32 w1 = cvt_pk_bf16(p2, p3);
      *(uint2*)((char*)Plw + SWZB(lr, n * 32 + lh * 8)) = make_uint2(w0, w1);
    }

    // O += P V
    __builtin_amdgcn_s_setprio(1);
#pragma unroll
    for (int kk = 0; kk < 4; ++kk) {
      sh8 pf = *(const sh8*)((const char*)Plw + SWZB(lr, kk * 64 + lh * 16));
#pragma unroll
      for (int n = 0; n < 4; ++n) {
        sh8 vf = *(const sh8*)((const char*)Vl[cur] + SWZB(n * 16 + lr, kk * 64 + lh * 16));
        oacc[n] = mfma16(pf, vf, oacc[n]);
      }
    }
    __builtin_amdgcn_s_setprio(0);

    if (it < 7) STAGE_WRITE(cur ^ 1)
    __syncthreads();
  }
#undef STAGE_LOAD
#undef STAGE_WRITE

  // total lsum for q = lr (reduce the 4 lh replicas)
  lsum += __shfl_xor(lsum, 16);
  lsum += __shfl_xor(lsum, 32);

  const int bb = bh >> 3, h = bh & 7;
#pragma unroll
  for (int r = 0; r < 4; ++r) {
    int row = qt * 128 + w * 16 + lh * 4 + r;
    float inv = 1.f / __shfl(lsum, lh * 4 + r);    // sum for q = lh*4+r
    u16* orow = Ob + (bb * SEQ + row) * HD + h * 64;
#pragma unroll
    for (int n = 0; n < 4; ++n)
      orow[n * 16 + lr] = f2bf(oacc[n][r] * inv);
  }
}

// ---- K3: out = a @ Wo^T + bo (MFMA; bf16 Wo pre-converted in k_prep) ----
__global__ __launch_bounds__(256) void k_oproj_mfma(const u16* __restrict__ A,
    const u16* __restrict__ W, const float* __restrict__ bo,
    float* __restrict__ out) {
  const int nb = blockIdx.x, ob = blockIdx.y;
  const int tid = threadIdx.x, w = tid >> 6, l = tid & 63;
  const int lr = l & 15, lh = l >> 4;
  __shared__ u16 Al[64 * 64];
  __shared__ u16 Wl[64 * 64];
  f4 acc[4];
#pragma unroll
  for (int n = 0; n < 4; ++n) acc[n] = (f4){0.f, 0.f, 0.f, 0.f};
  for (int ch = 0; ch < 8; ++ch) {
    __syncthreads();
#pragma unroll
    for (int i = 0; i < 2; ++i) {
      int idx = i * 256 + tid;
      int r = idx >> 3, c8 = idx & 7;
      *(sh8*)((char*)Al + SWZA(r, c8 * 16)) =
          *(const sh8*)(A + (nb * 64 + r) * HD + ch * 64 + c8 * 8);
      *(sh8*)((char*)Wl + SWZA(r, c8 * 16)) =
          *(const sh8*)(W + (ob * 64 + r) * HD + ch * 64 + c8 * 8);
    }
    __syncthreads();
#pragma unroll
    for (int kk = 0; kk < 2; ++kk) {
      sh8 af = *(const sh8*)((const char*)Al + SWZA(w * 16 + lr, kk * 64 + lh * 16));
#pragma unroll
      for (int n = 0; n < 4; ++n) {
        sh8 wf = *(const sh8*)((const char*)Wl + SWZA(n * 16 + lr, kk * 64 + lh * 16));
        acc[n] = mfma16(af, wf, acc[n]);
      }
    }
  }
#pragma unroll
  for (int r = 0; r < 4; ++r) {
    int row = nb * 64 + w * 16 + lh * 4 + r;
#pragma unroll
    for (int n = 0; n < 4; ++n) {
      int col = ob * 64 + n * 16 + lr;
      out[row * HD + col] = acc[n][r] + bo[col];
    }
  }
}

// ---------------- launch ----------------
extern "C" void kernel_launch(void* const* d_in, const int* in_sizes, int n_in,
                              void* d_out, int out_size, void* d_ws, size_t ws_size,
                              hipStream_t stream) {
  const float* x    = (const float*)d_in[0];
  const float* Wp   = (const float*)d_in[1];
  const float* bp   = (const float*)d_in[2];
  const float* ln_g = (const float*)d_in[3];
  const float* ln_b = (const float*)d_in[4];
  const float* qw   = (const float*)d_in[5];
  const float* qe   = (const float*)d_in[6];
  const float* qg   = (const float*)d_in[7];
  const float* qb_  = (const float*)d_in[8];
  const float* kw   = (const float*)d_in[9];
  const float* ke   = (const float*)d_in[10];
  const float* kg   = (const float*)d_in[11];
  const float* kb_  = (const float*)d_in[12];
  const float* vw   = (const float*)d_in[13];
  const float* ve   = (const float*)d_in[14];
  const float* vg   = (const float*)d_in[15];
  const float* vb_  = (const float*)d_in[16];
  const float* Wq   = (const float*)d_in[17];
  const float* bq   = (const float*)d_in[18];
  const float* Wk   = (const float*)d_in[19];
  const float* bk   = (const float*)d_in[20];
  const float* Wv   = (const float*)d_in[21];
  const float* bv   = (const float*)d_in[22];
  const float* Wo   = (const float*)d_in[23];
  const float* bo   = (const float*)d_in[24];

  float* ws   = (float*)d_ws;
  float* Mbuf = ws;                        // 9216 f
  u16* qb  = (u16*)(Mbuf + 9216);          // 32*1024*64 u16
  u16* kb  = qb + 32 * SEQ * HDD;
  u16* vtb = kb + 32 * SEQ * HDD;
  u16* ab  = vtb + 32 * SEQ * HDD;         // 4096*512 u16
  u16* wob = ab + NROWS * HD;              // 512*512 u16

  k_prep<<<11, 256, 0, stream>>>(qw, qe, qg, qb_, kw, ke, kg, kb_,
                                 vw, ve, vg, vb_, Wo, Mbuf, wob);
  k_front<<<NROWS / 4, 256, 0, stream>>>(x, Wp, bp, ln_g, ln_b, Mbuf,
                                         Wq, bq, Wk, bk, Wv, bv, qb, kb, vtb);
  k_attn_mfma<<<256, 512, 0, stream>>>(qb, kb, vtb, ab);
  dim3 go(NROWS / 64, HD / 64);
  k_oproj_mfma<<<go, 256, 0, stream>>>(ab, wob, bo, (float*)d_out);
}

// Round 18
// 69.967 us; speedup vs baseline: 1.1547x; 1.0127x over previous
//
#include <hip/hip_runtime.h>
#include <hip/hip_bf16.h>
#include <math.h>

#define NROWS 4096
#define HD 512
#define HEADS 8
#define HDD 64
#define SEQ 1024
#define QSCALE 0.18033688011112042f   // 0.125 * log2(e)

typedef unsigned short u16;
typedef unsigned int u32;
typedef unsigned long long u64;
typedef __attribute__((ext_vector_type(8))) short sh8;   // 8 bf16 (4 VGPRs)
typedef __attribute__((ext_vector_type(4))) float f4;    // MFMA accumulator

__device__ __forceinline__ f4 mfma16(sh8 a, sh8 b, f4 c) {
  return __builtin_amdgcn_mfma_f32_16x16x32_bf16(a, b, c, 0, 0, 0);
}

__device__ __forceinline__ u16 f2bf(float x) {
  union { float f; unsigned u; } v; v.f = x;
  unsigned r = v.u + 0x7fff + ((v.u >> 16) & 1);   // RNE
  return (u16)(r >> 16);
}

// packed fp32x2 -> bf16x2 (lo = first arg), 1 VALU op (T12 recipe)
__device__ __forceinline__ u32 cvt_pk_bf16(float lo, float hi) {
  u32 r;
  asm("v_cvt_pk_bf16_f32 %0, %1, %2" : "=v"(r) : "v"(lo), "v"(hi));
  return r;
}

// XOR swizzles (spread same-column b128 reads across 8 16B slots)
#define SWZA(r, cb) ((((r) * 128) + (cb)) ^ (((r) & 7) << 4))   // 128B rows
#define SWZB(r, cb) ((((r) * 256) + (cb)) ^ (((r) & 7) << 4))   // 256B rows

// ---------------- K0: prep ----------------
// blocks 0..2 : circuit -> U -> M[c][12][16][16]
// blocks 3..10: convert Wo (fp32 512x512) -> bf16 once
__global__ __launch_bounds__(256) void k_prep(
    const float* __restrict__ qw, const float* __restrict__ qe,
    const float* __restrict__ qg, const float* __restrict__ qb,
    const float* __restrict__ kw, const float* __restrict__ ke,
    const float* __restrict__ kg, const float* __restrict__ kb,
    const float* __restrict__ vw, const float* __restrict__ ve,
    const float* __restrict__ vg, const float* __restrict__ vb,
    const float* __restrict__ Wo, float* __restrict__ Mout,
    u16* __restrict__ Wob) {
  const int c = blockIdx.x;
  const int tid = threadIdx.x;

  if (c >= 3) {                        // ---- Wo conversion ----
    const int base = (c - 3) * 32768 + tid * 128;
#pragma unroll
    for (int i = 0; i < 16; ++i) {
      const float* src = Wo + base + i * 8;
      float4 f0 = *(const float4*)src;
      float4 f1 = *(const float4*)(src + 4);
      uint4 v;
      v.x = cvt_pk_bf16(f0.x, f0.y);
      v.y = cvt_pk_bf16(f0.z, f0.w);
      v.z = cvt_pk_bf16(f1.x, f1.y);
      v.w = cvt_pk_bf16(f1.z, f1.w);
      *(uint4*)(Wob + base + i * 8) = v;
    }
    return;
  }

  __shared__ float aC[32], aS[32];
  __shared__ float GT[60][8];
  __shared__ int   GM[60][2];
  __shared__ float PF[3][16][2];
  __shared__ float SR[16][17], SI[16][17];
  __shared__ float TS[16], TI[16];
  __shared__ float Ur[256], Ui[256];

  const float* w = (c == 0) ? qw : (c == 1) ? kw : vw;
  const float* e = (c == 0) ? qe : (c == 1) ? ke : ve;
  const float* g = (c == 0) ? qg : (c == 1) ? kg : vg;
  const float* b = (c == 0) ? qb : (c == 1) ? kb : vb;

  if (tid < 30) {
    float ang = (tid < 12) ? w[tid] : (tid < 24) ? e[tid - 12]
               : (tid < 27) ? g[tid - 24] : b[tid - 27];
    float s_, c_;
    sincosf(0.5f * ang, &s_, &c_);
    aC[tid] = c_; aS[tid] = s_;
  }
  __syncthreads();

  if (tid < 60) {
    int L = tid / 20, s5 = tid % 20;
    int typ, aidx, M, C;
    if (s5 < 12) {
      int q = s5 / 3; typ = s5 % 3; aidx = L * 4 + q; M = 8 >> q; C = 0;
    } else if (s5 < 16) {
      int q = s5 - 12; typ = 0; aidx = 12 + L * 4 + q;
      C = 8 >> q; M = 8 >> ((q + 1) & 3);
    } else {
      int q = s5 - 16; typ = 0; aidx = 27 + L; M = 8 >> q; C = 0;
    }
    float cc = aC[aidx], ss = aS[aidx];
    float u0r = cc, u0i = 0.f, u1r = 0.f, u1i = 0.f,
          u2r = 0.f, u2i = 0.f, u3r = cc, u3i = 0.f;
    if (typ == 0)      { u1i = -ss; u2i = -ss; }
    else if (typ == 1) { u1r = -ss; u2r = ss; }
    else               { u0i = -ss; u3i = ss; }
    GT[tid][0] = u0r; GT[tid][1] = u0i; GT[tid][2] = u1r; GT[tid][3] = u1i;
    GT[tid][4] = u2r; GT[tid][5] = u2i; GT[tid][6] = u3r; GT[tid][7] = u3i;
    GM[tid][0] = M; GM[tid][1] = C;
  }
  if (tid >= 64 && tid < 112) {
    int idx = tid - 64, L = idx >> 4, a = idx & 15;
    float cg = aC[24 + L], sg = aS[24 + L];
    float c2 = cg * cg - sg * sg, s2 = 2.f * cg * sg;
    float c3 = cg * c2 - sg * s2, s3 = cg * s2 + sg * c2;
    int u = (a ^ (a >> 1)) & 7;
    int n = (u & 1) + ((u >> 1) & 1) + ((u >> 2) & 1);
    PF[L][a][0] = (n == 0 || n == 3) ? c3 : cg;
    PF[L][a][1] = (n == 0) ? -s3 : (n == 1) ? -sg : (n == 2) ? sg : s3;
  }
  for (int i = tid; i < 256; i += 256) {
    SR[i >> 4][i & 15] = (i >> 4) == (i & 15) ? 1.f : 0.f;
    SI[i >> 4][i & 15] = 0.f;
  }
  __syncthreads();

  const int p = tid >> 4, col = tid & 15;
  for (int L = 0; L < 3; ++L) {
    for (int s5 = 0; s5 < 16; ++s5) {
      if (tid < 128) {
        int gi = L * 20 + s5;
        const float* u = GT[gi];
        int M = GM[gi][0], C = GM[gi][1];
        int lo = p & (M - 1);
        int a = ((p - lo) << 1) | lo;
        int bb = a | M;
        bool act = (C == 0) | ((a & C) != 0);
        float ar = SR[a][col], ai = SI[a][col];
        float br = SR[bb][col], bi = SI[bb][col];
        float nar = u[0]*ar - u[1]*ai + u[2]*br - u[3]*bi;
        float nai = u[0]*ai + u[1]*ar + u[2]*bi + u[3]*br;
        float nbr = u[4]*ar - u[5]*ai + u[6]*br - u[7]*bi;
        float nbi = u[4]*ai + u[5]*ar + u[6]*bi + u[7]*br;
        SR[a][col]  = act ? nar : ar;  SI[a][col]  = act ? nai : ai;
        SR[bb][col] = act ? nbr : br;  SI[bb][col] = act ? nbi : bi;
      }
      __syncthreads();
    }
    if (tid < 16) {
      float sR = 0.f, sI = 0.f;
      for (int a = 0; a < 16; ++a) { sR += SR[a][tid]; sI += SI[a][tid]; }
      TS[tid] = sR * 0.125f; TI[tid] = sI * 0.125f;
    }
    __syncthreads();
    if (tid < 128) {
      for (int k = 0; k < 2; ++k) {
        int a = 2 * p + k;
        float vr = SR[a][col] - TS[col];
        float vi = SI[a][col] - TI[col];
        float pc = PF[L][a][0], ps = PF[L][a][1];
        SR[a][col] = vr * pc - vi * ps;
        SI[a][col] = vr * ps + vi * pc;
      }
    }
    __syncthreads();
    for (int s5 = 16; s5 < 20; ++s5) {
      if (tid < 128) {
        int gi = L * 20 + s5;
        const float* u = GT[gi];
        int M = GM[gi][0];
        int lo = p & (M - 1);
        int a = ((p - lo) << 1) | lo;
        int bb = a | M;
        float ar = SR[a][col], ai = SI[a][col];
        float br = SR[bb][col], bi = SI[bb][col];
        SR[a][col]  = u[0]*ar - u[1]*ai + u[2]*br - u[3]*bi;
        SI[a][col]  = u[0]*ai + u[1]*ar + u[2]*bi + u[3]*br;
        SR[bb][col] = u[4]*ar - u[5]*ai + u[6]*br - u[7]*bi;
        SI[bb][col] = u[4]*ai + u[5]*ar + u[6]*bi + u[7]*br;
      }
      __syncthreads();
    }
  }

  for (int i = tid; i < 256; i += 256) {
    Ur[i] = SR[i >> 4][i & 15];
    Ui[i] = SI[i >> 4][i & 15];
  }
  __syncthreads();

  if (tid < 192) {
    const int j = tid >> 4, a = tid & 15;
    const int typ = j >> 2;
    const int Mm = 8 >> (j & 3);
    float ax[4] = {0.f,0.f,0.f,0.f}, ay[4] = {0.f,0.f,0.f,0.f},
          az[4] = {0.f,0.f,0.f,0.f}, aw[4] = {0.f,0.f,0.f,0.f};
#pragma clang loop unroll_count(4)
    for (int k = 0; k < 16; ++k) {
      float uar = Ur[k * 16 + a], uai = Ui[k * 16 + a];
      int k2; float cR, cI;
      if (typ == 0)      { k2 = k;      float z = (k & Mm) ? -1.f : 1.f; cR = z*uar; cI = z*uai; }
      else if (typ == 1) { k2 = k ^ Mm; cR = uar; cI = uai; }
      else               { k2 = k ^ Mm; float sg = (k & Mm) ? 1.f : -1.f; cR = sg*uai; cI = -sg*uar; }
      const float* ur2 = Ur + k2 * 16;
      const float* ui2 = Ui + k2 * 16;
#pragma unroll
      for (int i = 0; i < 4; ++i) {
        ax[i] += cR * ur2[i*4+0] + cI * ui2[i*4+0];
        ay[i] += cR * ur2[i*4+1] + cI * ui2[i*4+1];
        az[i] += cR * ur2[i*4+2] + cI * ui2[i*4+2];
        aw[i] += cR * ur2[i*4+3] + cI * ui2[i*4+3];
      }
    }
    float* dst = Mout + ((c * 12 + j) * 16 + a) * 16;
#pragma unroll
    for (int i = 0; i < 4; ++i)
      ((float4*)dst)[i] = make_float4(ax[i], ay[i], az[i], aw[i]);
  }
}

// ---- K1: front: LN(+psi in-wave) -> t -> QKV, 1024 blocks x 4 rows ----
// 2 barriers (was 3): phase-B bubble removed; psi computed on lane 0 of the
// owning wave right after its LN.
__global__ __launch_bounds__(256) void k_front(const float* __restrict__ x,
    const float* __restrict__ Wp, const float* __restrict__ bp,
    const float* __restrict__ ln_g, const float* __restrict__ ln_b,
    const float* __restrict__ Mg,
    const float* __restrict__ Wq, const float* __restrict__ bq,
    const float* __restrict__ Wk, const float* __restrict__ bk,
    const float* __restrict__ Wv, const float* __restrict__ bv,
    u16* __restrict__ Qo, u16* __restrict__ Ko, u16* __restrict__ Vto) {
  const int rb = blockIdx.x;
  const int tid = threadIdx.x;
  const int w = tid >> 6, lane = tid & 63;
  __shared__ float psil[4][16];
  __shared__ float tt[3][4][12];

  // ---- A: LN(tanh(x @ Wp^T + bp)) + psi, wave w owns row rb*4+w ----
  {
    const float* xr = x + (rb * 4 + w) * HD + lane * 8;
    float4 xa = *(const float4*)xr, xb = *(const float4*)(xr + 4);
    float acc[4];
#pragma unroll
    for (int j = 0; j < 4; ++j) {
      const float* wr = Wp + j * HD + lane * 8;
      float4 wa = *(const float4*)wr, wb = *(const float4*)(wr + 4);
      acc[j] = xa.x*wa.x + xa.y*wa.y + xa.z*wa.z + xa.w*wa.w
             + xb.x*wb.x + xb.y*wb.y + xb.z*wb.z + xb.w*wb.w;
    }
#pragma unroll
    for (int j = 0; j < 4; ++j)
#pragma unroll
      for (int off = 32; off >= 1; off >>= 1)
        acc[j] += __shfl_xor(acc[j], off);
    if (lane == 0) {
      float v0 = tanhf(acc[0] + bp[0]);
      float v1 = tanhf(acc[1] + bp[1]);
      float v2 = tanhf(acc[2] + bp[2]);
      float v3 = tanhf(acc[3] + bp[3]);
      float mu = 0.25f * (v0 + v1 + v2 + v3);
      float d0 = v0 - mu, d1 = v1 - mu, d2 = v2 - mu, d3 = v3 - mu;
      float inv = rsqrtf(0.25f * (d0*d0 + d1*d1 + d2*d2 + d3*d3) + 1e-5f);
      float p0 = d0 * inv * ln_g[0] + ln_b[0];
      float p1 = d1 * inv * ln_g[1] + ln_b[1];
      float p2 = d2 * inv * ln_g[2] + ln_b[2];
      float p3 = d3 * inv * ln_g[3] + ln_b[3];
      float cs[4], sn[4];
      sincosf(0.5f * p0, &sn[0], &cs[0]);
      sincosf(0.5f * p1, &sn[1], &cs[1]);
      sincosf(0.5f * p2, &sn[2], &cs[2]);
      sincosf(0.5f * p3, &sn[3], &cs[3]);
      float q01[4] = {cs[0]*cs[1], cs[0]*sn[1], sn[0]*cs[1], sn[0]*sn[1]};
      float q23[4] = {cs[2]*cs[3], cs[2]*sn[3], sn[2]*cs[3], sn[2]*sn[3]};
#pragma unroll
      for (int a = 0; a < 16; ++a) psil[w][a] = q01[a >> 2] * q23[a & 3];
    }
  }
  __syncthreads();

  // ---- C: t[c][r][j] = psi^T M[c][j] psi  (144 threads; M broadcast via L2)
  if (tid < 144) {
    const int c = tid / 48, rem = tid - c * 48, j = rem >> 2, r = rem & 3;
    float psi[16];
#pragma unroll
    for (int a = 0; a < 16; ++a) psi[a] = psil[r][a];
    const float4* Mj = (const float4*)(Mg + (c * 12 + j) * 256);
    float y = 0.f;
#pragma unroll
    for (int a = 0; a < 16; ++a) {
      float rsum = 0.f;
#pragma unroll
      for (int i = 0; i < 4; ++i) {
        float4 m4 = Mj[a * 4 + i];
        rsum += m4.x*psi[i*4] + m4.y*psi[i*4+1] + m4.z*psi[i*4+2] + m4.w*psi[i*4+3];
      }
      y += psi[a] * rsum;
    }
    tt[c][r][j] = y;
  }
  __syncthreads();

  // ---- D: QKV projection; thread owns output col pair (2tid, 2tid+1) ----
  const int o0 = tid * 2;
  const int b = rb >> 8, ss0 = (rb & 255) * 4;
  const int h = o0 >> 6, d = o0 & 63;
#pragma unroll
  for (int c = 0; c < 3; ++c) {
    const float* W  = (c == 0) ? Wq : (c == 1) ? Wk : Wv;
    const float* bb = (c == 0) ? bq : (c == 1) ? bk : bv;
    float4 w0a = *(const float4*)(W + o0 * 12);
    float4 w0b = *(const float4*)(W + o0 * 12 + 4);
    float4 w0c = *(const float4*)(W + o0 * 12 + 8);
    float4 w1a = *(const float4*)(W + o0 * 12 + 12);
    float4 w1b = *(const float4*)(W + o0 * 12 + 16);
    float4 w1c = *(const float4*)(W + o0 * 12 + 20);
    float b0 = bb[o0], b1 = bb[o0 + 1];
    float r0[4], r1[4];
#pragma unroll
    for (int r = 0; r < 4; ++r) {
      const float* t = tt[c][r];
      r0[r] = b0 + t[0]*w0a.x + t[1]*w0a.y + t[2]*w0a.z + t[3]*w0a.w
                 + t[4]*w0b.x + t[5]*w0b.y + t[6]*w0b.z + t[7]*w0b.w
                 + t[8]*w0c.x + t[9]*w0c.y + t[10]*w0c.z + t[11]*w0c.w;
      r1[r] = b1 + t[0]*w1a.x + t[1]*w1a.y + t[2]*w1a.z + t[3]*w1a.w
                 + t[4]*w1b.x + t[5]*w1b.y + t[6]*w1b.z + t[7]*w1b.w
                 + t[8]*w1c.x + t[9]*w1c.y + t[10]*w1c.z + t[11]*w1c.w;
    }
    if (c == 0) {
      u16* qrow = Qo + ((b * HEADS + h) * SEQ + ss0) * HDD + d;
#pragma unroll
      for (int r = 0; r < 4; ++r)
        *(u32*)(qrow + r * HDD) =
            (u32)f2bf(r0[r] * QSCALE) | ((u32)f2bf(r1[r] * QSCALE) << 16);
    } else if (c == 1) {
      u16* krow = Ko + ((b * HEADS + h) * SEQ + ss0) * HDD + d;
#pragma unroll
      for (int r = 0; r < 4; ++r)
        *(u32*)(krow + r * HDD) = (u32)f2bf(r0[r]) | ((u32)f2bf(r1[r]) << 16);
    } else {
      u64 v0 = (u64)((u32)f2bf(r0[0]) | ((u32)f2bf(r0[1]) << 16)) |
               ((u64)((u32)f2bf(r0[2]) | ((u32)f2bf(r0[3]) << 16)) << 32);
      u64 v1 = (u64)((u32)f2bf(r1[0]) | ((u32)f2bf(r1[1]) << 16)) |
               ((u64)((u32)f2bf(r1[2]) | ((u32)f2bf(r1[3]) << 16)) << 32);
      *(u64*)(Vto + (b * 512 + o0) * SEQ + ss0) = v0;
      *(u64*)(Vto + (b * 512 + o0 + 1) * SEQ + ss0) = v1;
    }
  }
}

// ------- K2: MFMA flash attention, swapped QK^T, q-tile 128, 8 waves --------
// grid 256 (XCD-swizzled -> (qt 0..7, bh 0..31)); 512 thr; chunk 128 dbuf;
// 96 KB LDS. In-kernel normalization.
__global__ __launch_bounds__(512) void k_attn_mfma(const u16* __restrict__ Q,
    const u16* __restrict__ K, const u16* __restrict__ Vt,
    u16* __restrict__ Ob) {
  const int lin = (blockIdx.x & 7) * 32 + (blockIdx.x >> 3);
  const int bh = lin >> 3, qt = lin & 7;
  const int tid = threadIdx.x, w = tid >> 6, l = tid & 63;
  const int lr = l & 15, lh = l >> 4;

  __shared__ u16 Kl[2][128 * 64];    // [key][d]   128B rows, SWZA  (32 KB)
  __shared__ u16 Vl[2][64 * 128];    // [d][key]   256B rows, SWZB  (32 KB)
  __shared__ u16 Pl[8][16 * 128];    // per-wave P [q][key] SWZB    (32 KB)

  const u16* Qb = Q + (bh * SEQ + qt * 128) * HDD;
  const u16* Kb = K + bh * SEQ * HDD;
  const u16* Vb = Vt + bh * HDD * SEQ;
  u16* Plw = Pl[w];

  sh8 qf[2];
#pragma unroll
  for (int kk = 0; kk < 2; ++kk)
    qf[kk] = *(const sh8*)(Qb + (w * 16 + lr) * HDD + kk * 32 + lh * 8);

  f4 oacc[4];
  float lsum = 0.f;                  // partial row-sum for q = lr
#pragma unroll
  for (int n = 0; n < 4; ++n) oacc[n] = (f4){0.f, 0.f, 0.f, 0.f};

  sh8 kreg[2], vreg[2];

#define STAGE_LOAD(ch) { \
    _Pragma("unroll") \
    for (int i = 0; i < 2; ++i) { \
      int idx = i * 512 + tid; \
      kreg[i] = *(const sh8*)(Kb + ((ch) * 128 + (idx >> 3)) * HDD + (idx & 7) * 8); \
      vreg[i] = *(const sh8*)(Vb + (idx >> 4) * SEQ + (ch) * 128 + (idx & 15) * 8); \
    } }
#define STAGE_WRITE(buf) { \
    _Pragma("unroll") \
    for (int i = 0; i < 2; ++i) { \
      int idx = i * 512 + tid; \
      *(sh8*)((char*)Kl[buf] + SWZA(idx >> 3, (idx & 7) * 16)) = kreg[i]; \
      *(sh8*)((char*)Vl[buf] + SWZB(idx >> 4, (idx & 15) * 16)) = vreg[i]; \
    } }

  STAGE_LOAD(0)
  STAGE_WRITE(0)
  __syncthreads();

  for (int it = 0; it < 8; ++it) {
    const int cur = it & 1;
    if (it < 7) STAGE_LOAD(it + 1)       // issue early; lands under compute

    f4 sacc[8];
#pragma unroll
    for (int n = 0; n < 8; ++n) sacc[n] = (f4){0.f, 0.f, 0.f, 0.f};
    __builtin_amdgcn_s_setprio(1);
#pragma unroll
    for (int kk = 0; kk < 2; ++kk) {
#pragma unroll
      for (int n = 0; n < 8; ++n) {
        sh8 kf = *(const sh8*)((const char*)Kl[cur] + SWZA(n * 16 + lr, kk * 64 + lh * 16));
        sacc[n] = mfma16(kf, qf[kk], sacc[n]);
      }
    }
    __builtin_amdgcn_s_setprio(0);

#pragma unroll
    for (int n = 0; n < 8; ++n) {
      float p0 = exp2f(sacc[n][0]);
      float p1 = exp2f(sacc[n][1]);
      float p2 = exp2f(sacc[n][2]);
      float p3 = exp2f(sacc[n][3]);
      lsum += (p0 + p1) + (p2 + p3);
      u32 w0 = cvt_pk_bf16(p0, p1);
      u32 w1 = cvt_pk_bf16(p2, p3);
      *(uint2*)((char*)Plw + SWZB(lr, n * 32 + lh * 8)) = make_uint2(w0, w1);
    }

    __builtin_amdgcn_s_setprio(1);
#pragma unroll
    for (int kk = 0; kk < 4; ++kk) {
      sh8 pf = *(const sh8*)((const char*)Plw + SWZB(lr, kk * 64 + lh * 16));
#pragma unroll
      for (int n = 0; n < 4; ++n) {
        sh8 vf = *(const sh8*)((const char*)Vl[cur] + SWZB(n * 16 + lr, kk * 64 + lh * 16));
        oacc[n] = mfma16(pf, vf, oacc[n]);
      }
    }
    __builtin_amdgcn_s_setprio(0);

    if (it < 7) STAGE_WRITE(cur ^ 1)
    __syncthreads();
  }
#undef STAGE_LOAD
#undef STAGE_WRITE

  lsum += __shfl_xor(lsum, 16);
  lsum += __shfl_xor(lsum, 32);

  const int bb = bh >> 3, h = bh & 7;
#pragma unroll
  for (int r = 0; r < 4; ++r) {
    int row = qt * 128 + w * 16 + lh * 4 + r;
    float inv = 1.f / __shfl(lsum, lh * 4 + r);
    u16* orow = Ob + (bb * SEQ + row) * HD + h * 64;
#pragma unroll
    for (int n = 0; n < 4; ++n)
      orow[n * 16 + lr] = f2bf(oacc[n][r] * inv);
  }
}

// ---- K3: out = a @ Wo^T + bo (MFMA; bf16 Wo pre-converted in k_prep) ----
__global__ __launch_bounds__(256) void k_oproj_mfma(const u16* __restrict__ A,
    const u16* __restrict__ W, const float* __restrict__ bo,
    float* __restrict__ out) {
  const int nb = blockIdx.x, ob = blockIdx.y;
  const int tid = threadIdx.x, w = tid >> 6, l = tid & 63;
  const int lr = l & 15, lh = l >> 4;
  __shared__ u16 Al[64 * 64];
  __shared__ u16 Wl[64 * 64];
  f4 acc[4];
#pragma unroll
  for (int n = 0; n < 4; ++n) acc[n] = (f4){0.f, 0.f, 0.f, 0.f};
  for (int ch = 0; ch < 8; ++ch) {
    __syncthreads();
#pragma unroll
    for (int i = 0; i < 2; ++i) {
      int idx = i * 256 + tid;
      int r = idx >> 3, c8 = idx & 7;
      *(sh8*)((char*)Al + SWZA(r, c8 * 16)) =
          *(const sh8*)(A + (nb * 64 + r) * HD + ch * 64 + c8 * 8);
      *(sh8*)((char*)Wl + SWZA(r, c8 * 16)) =
          *(const sh8*)(W + (ob * 64 + r) * HD + ch * 64 + c8 * 8);
    }
    __syncthreads();
#pragma unroll
    for (int kk = 0; kk < 2; ++kk) {
      sh8 af = *(const sh8*)((const char*)Al + SWZA(w * 16 + lr, kk * 64 + lh * 16));
#pragma unroll
      for (int n = 0; n < 4; ++n) {
        sh8 wf = *(const sh8*)((const char*)Wl + SWZA(n * 16 + lr, kk * 64 + lh * 16));
        acc[n] = mfma16(af, wf, acc[n]);
      }
    }
  }
#pragma unroll
  for (int r = 0; r < 4; ++r) {
    int row = nb * 64 + w * 16 + lh * 4 + r;
#pragma unroll
    for (int n = 0; n < 4; ++n) {
      int col = ob * 64 + n * 16 + lr;
      out[row * HD + col] = acc[n][r] + bo[col];
    }
  }
}

// ---------------- launch ----------------
extern "C" void kernel_launch(void* const* d_in, const int* in_sizes, int n_in,
                              void* d_out, int out_size, void* d_ws, size_t ws_size,
                              hipStream_t stream) {
  const float* x    = (const float*)d_in[0];
  const float* Wp   = (const float*)d_in[1];
  const float* bp   = (const float*)d_in[2];
  const float* ln_g = (const float*)d_in[3];
  const float* ln_b = (const float*)d_in[4];
  const float* qw   = (const float*)d_in[5];
  const float* qe   = (const float*)d_in[6];
  const float* qg   = (const float*)d_in[7];
  const float* qb_  = (const float*)d_in[8];
  const float* kw   = (const float*)d_in[9];
  const float* ke   = (const float*)d_in[10];
  const float* kg   = (const float*)d_in[11];
  const float* kb_  = (const float*)d_in[12];
  const float* vw   = (const float*)d_in[13];
  const float* ve   = (const float*)d_in[14];
  const float* vg   = (const float*)d_in[15];
  const float* vb_  = (const float*)d_in[16];
  const float* Wq   = (const float*)d_in[17];
  const float* bq   = (const float*)d_in[18];
  const float* Wk   = (const float*)d_in[19];
  const float* bk   = (const float*)d_in[20];
  const float* Wv   = (const float*)d_in[21];
  const float* bv   = (const float*)d_in[22];
  const float* Wo   = (const float*)d_in[23];
  const float* bo   = (const float*)d_in[24];

  float* ws   = (float*)d_ws;
  float* Mbuf = ws;                        // 9216 f
  u16* qb  = (u16*)(Mbuf + 9216);          // 32*1024*64 u16
  u16* kb  = qb + 32 * SEQ * HDD;
  u16* vtb = kb + 32 * SEQ * HDD;
  u16* ab  = vtb + 32 * SEQ * HDD;         // 4096*512 u16
  u16* wob = ab + NROWS * HD;              // 512*512 u16

  k_prep<<<11, 256, 0, stream>>>(qw, qe, qg, qb_, kw, ke, kg, kb_,
                                 vw, ve, vg, vb_, Wo, Mbuf, wob);
  k_front<<<NROWS / 4, 256, 0, stream>>>(x, Wp, bp, ln_g, ln_b, Mbuf,
                                         Wq, bq, Wk, bk, Wv, bv, qb, kb, vtb);
  k_attn_mfma<<<256, 512, 0, stream>>>(qb, kb, vtb, ab);
  dim3 go(NROWS / 64, HD / 64);
  k_oproj_mfma<<<go, 256, 0, stream>>>(ab, wob, bo, (float*)d_out);
}